// Round 1
// baseline (2377.662 us; speedup 1.0000x reference)
//
#include <hip/hip_runtime.h>

#define N_NODES 50000
#define N_EDGES 800000
#define F_IN    64
#define H_DIM   128
#define N_GRAPHS 512
#define LN_EPS  1e-5f

// ---------------------------------------------------------------------------
// degree: deg[dst] += 1 per edge
__global__ void deg_kernel(const int* __restrict__ dst, float* __restrict__ deg) {
    int e = blockIdx.x * blockDim.x + threadIdx.x;
    if (e < N_EDGES) atomicAdd(&deg[dst[e]], 1.0f);
}

// ---------------------------------------------------------------------------
// elementwise add (combine Wr + Rres, bl + bres)
__global__ void addw_kernel(const float* __restrict__ a, const float* __restrict__ b,
                            float* __restrict__ o, int n) {
    int i = blockIdx.x * blockDim.x + threadIdx.x;
    if (i < n) o[i] = a[i] + b[i];
}

// ---------------------------------------------------------------------------
// scatter-add: agg[dst] += h[src], F features, float4 per thread
template <int F>
__global__ void scatter_kernel(const float* __restrict__ h, const int* __restrict__ src,
                               const int* __restrict__ dst, float* __restrict__ agg) {
    constexpr int F4 = F / 4;
    int tid = blockIdx.x * blockDim.x + threadIdx.x;
    int e = tid / F4;
    int c = tid % F4;
    if (e >= N_EDGES) return;
    int s = src[e];
    int d = dst[e];
    const float4 v = *reinterpret_cast<const float4*>(&h[(size_t)s * F + c * 4]);
    float* out = &agg[(size_t)d * F + c * 4];
    atomicAdd(out + 0, v.x);
    atomicAdd(out + 1, v.y);
    atomicAdd(out + 2, v.z);
    atomicAdd(out + 3, v.w);
}

// ---------------------------------------------------------------------------
// wave (64-lane) reduction
__device__ __forceinline__ float waveReduceSum(float v) {
    #pragma unroll
    for (int off = 32; off > 0; off >>= 1) v += __shfl_xor(v, off, 64);
    return v;
}

// ---------------------------------------------------------------------------
// fused node update:
//   out = LN( (agg/deg) @ Wl + hin @ Wc + bc ) [*ReLU]
// 1 wave per block; thread handles columns j and j+64; NB=8 nodes per iter.
template <int K, bool RELU>
__launch_bounds__(64)
__global__ void layer_kernel(const float* __restrict__ agg,   // [N,K] (sum, pre-division)
                             const float* __restrict__ hin,   // [N,K]
                             const float* __restrict__ deg,   // [N]
                             const float* __restrict__ Wl,    // [K,128]
                             const float* __restrict__ Wc,    // [K,128]
                             const float* __restrict__ bc,    // [128]
                             const float* __restrict__ ln_g,  // [128]
                             const float* __restrict__ ln_b,  // [128]
                             float* __restrict__ hout,        // [N,128]
                             int nNodes) {
    constexpr int NB = 8;
    constexpr int K4 = K / 4;
    __shared__ __align__(16) float sAgg[NB][K];
    __shared__ __align__(16) float sX[NB][K];

    const int j = threadIdx.x;           // 0..63
    const int j2 = j + 64;

    const float g0 = ln_g[j],  b0 = ln_b[j];
    const float g1 = ln_g[j2], b1 = ln_b[j2];
    const float bias0 = bc[j], bias1 = bc[j2];

    for (int base = blockIdx.x * NB; base < nNodes; base += gridDim.x * NB) {
        // ---- stage NB rows of agg and hin into LDS (float4) ----
        #pragma unroll
        for (int t = j; t < NB * K4; t += 64) {
            int n = t / K4, c = t % K4;
            *reinterpret_cast<float4*>(&sAgg[n][c * 4]) =
                *reinterpret_cast<const float4*>(&agg[(size_t)(base + n) * K + c * 4]);
            *reinterpret_cast<float4*>(&sX[n][c * 4]) =
                *reinterpret_cast<const float4*>(&hin[(size_t)(base + n) * K + c * 4]);
        }
        __syncthreads();

        // ---- accumulate ----
        float accA0[NB], accA1[NB], accX0[NB], accX1[NB];
        #pragma unroll
        for (int n = 0; n < NB; ++n) { accA0[n] = 0.f; accA1[n] = 0.f; accX0[n] = 0.f; accX1[n] = 0.f; }

        for (int k = 0; k < K; k += 4) {
            float wl0[4], wl1[4], wc0[4], wc1[4];
            #pragma unroll
            for (int u = 0; u < 4; ++u) {
                wl0[u] = Wl[(size_t)(k + u) * H_DIM + j];
                wl1[u] = Wl[(size_t)(k + u) * H_DIM + j2];
                wc0[u] = Wc[(size_t)(k + u) * H_DIM + j];
                wc1[u] = Wc[(size_t)(k + u) * H_DIM + j2];
            }
            #pragma unroll
            for (int n = 0; n < NB; ++n) {
                const float4 ra = *reinterpret_cast<const float4*>(&sAgg[n][k]);
                const float4 rx = *reinterpret_cast<const float4*>(&sX[n][k]);
                accA0[n] = fmaf(ra.x, wl0[0], accA0[n]);
                accA0[n] = fmaf(ra.y, wl0[1], accA0[n]);
                accA0[n] = fmaf(ra.z, wl0[2], accA0[n]);
                accA0[n] = fmaf(ra.w, wl0[3], accA0[n]);
                accA1[n] = fmaf(ra.x, wl1[0], accA1[n]);
                accA1[n] = fmaf(ra.y, wl1[1], accA1[n]);
                accA1[n] = fmaf(ra.z, wl1[2], accA1[n]);
                accA1[n] = fmaf(ra.w, wl1[3], accA1[n]);
                accX0[n] = fmaf(rx.x, wc0[0], accX0[n]);
                accX0[n] = fmaf(rx.y, wc0[1], accX0[n]);
                accX0[n] = fmaf(rx.z, wc0[2], accX0[n]);
                accX0[n] = fmaf(rx.w, wc0[3], accX0[n]);
                accX1[n] = fmaf(rx.x, wc1[0], accX1[n]);
                accX1[n] = fmaf(rx.y, wc1[1], accX1[n]);
                accX1[n] = fmaf(rx.z, wc1[2], accX1[n]);
                accX1[n] = fmaf(rx.w, wc1[3], accX1[n]);
            }
        }

        // ---- finalize: invdeg, LayerNorm (wave-internal), write ----
        #pragma unroll
        for (int n = 0; n < NB; ++n) {
            const float dg = deg[base + n];
            const float invd = 1.0f / fmaxf(dg, 1.0f);
            float v0 = accX0[n] + bias0 + invd * accA0[n];
            float v1 = accX1[n] + bias1 + invd * accA1[n];
            const float sum = waveReduceSum(v0 + v1);
            const float mean = sum * (1.0f / H_DIM);
            const float d0 = v0 - mean, d1 = v1 - mean;
            const float ss = waveReduceSum(d0 * d0 + d1 * d1);
            const float rstd = rsqrtf(ss * (1.0f / H_DIM) + LN_EPS);
            float o0 = d0 * rstd * g0 + b0;
            float o1 = d1 * rstd * g1 + b1;
            if (RELU) { o0 = fmaxf(o0, 0.f); o1 = fmaxf(o1, 0.f); }
            hout[(size_t)(base + n) * H_DIM + j]  = o0;
            hout[(size_t)(base + n) * H_DIM + j2] = o1;
        }
        __syncthreads();
    }
}

// ---------------------------------------------------------------------------
// mean-pool per graph (atomic accumulate)
__global__ void pool_kernel(const float* __restrict__ h, const int* __restrict__ batch,
                            float* __restrict__ pooled, float* __restrict__ cnt) {
    int tid = blockIdx.x * blockDim.x + threadIdx.x;
    int i = tid >> 5;           // node
    int c = tid & 31;           // float4 chunk
    if (i >= N_NODES) return;
    int g = batch[i];
    const float4 v = *reinterpret_cast<const float4*>(&h[(size_t)i * H_DIM + c * 4]);
    float* p = &pooled[(size_t)g * H_DIM + c * 4];
    atomicAdd(p + 0, v.x);
    atomicAdd(p + 1, v.y);
    atomicAdd(p + 2, v.z);
    atomicAdd(p + 3, v.w);
    if (c == 0) atomicAdd(&cnt[g], 1.0f);
}

// ---------------------------------------------------------------------------
// final: out[g] = (pooled[g]/cnt[g]) . out_w + out_b
__global__ void final_kernel(const float* __restrict__ pooled, const float* __restrict__ cnt,
                             const float* __restrict__ ow, const float* __restrict__ ob,
                             float* __restrict__ out) {
    int gph = blockIdx.x;
    int lane = threadIdx.x;
    float s = pooled[(size_t)gph * H_DIM + lane] * ow[lane]
            + pooled[(size_t)gph * H_DIM + 64 + lane] * ow[64 + lane];
    s = waveReduceSum(s);
    if (lane == 0) out[gph] = s / fmaxf(cnt[gph], 1.0f) + ob[0];
}

// ---------------------------------------------------------------------------
static inline size_t align256(size_t x) { return (x + 255) & ~(size_t)255; }

extern "C" void kernel_launch(void* const* d_in, const int* in_sizes, int n_in,
                              void* d_out, int out_size, void* d_ws, size_t ws_size,
                              hipStream_t stream) {
    const float* x        = (const float*)d_in[0];
    const int*   eidx     = (const int*)d_in[1];
    const int*   batch    = (const int*)d_in[2];
    const float* lin_l0_w = (const float*)d_in[3];
    const float* lin_l0_b = (const float*)d_in[4];
    const float* lin_r0_w = (const float*)d_in[5];
    const float* res0_w   = (const float*)d_in[6];
    const float* res0_b   = (const float*)d_in[7];
    const float* ln0_g    = (const float*)d_in[8];
    const float* ln0_b    = (const float*)d_in[9];
    const float* lin_l1_w = (const float*)d_in[10];
    const float* lin_l1_b = (const float*)d_in[11];
    const float* lin_r1_w = (const float*)d_in[12];
    const float* res1_w   = (const float*)d_in[13];
    const float* res1_b   = (const float*)d_in[14];
    const float* ln1_g    = (const float*)d_in[15];
    const float* ln1_b    = (const float*)d_in[16];
    const float* out_w    = (const float*)d_in[17];
    const float* out_b    = (const float*)d_in[18];
    float* out = (float*)d_out;

    const int* src = eidx;
    const int* dst = eidx + N_EDGES;

    // workspace layout
    char* p = (char*)d_ws;
    float* deg    = (float*)p; p += align256((size_t)N_NODES * 4);
    float* agg    = (float*)p; p += align256((size_t)N_NODES * H_DIM * 4);   // also h1 (in place)
    float* h0     = (float*)p; p += align256((size_t)N_NODES * H_DIM * 4);
    float* Wc0    = (float*)p; p += align256((size_t)F_IN * H_DIM * 4);
    float* bc0    = (float*)p; p += align256((size_t)H_DIM * 4);
    float* Wc1    = (float*)p; p += align256((size_t)H_DIM * H_DIM * 4);
    float* bc1    = (float*)p; p += align256((size_t)H_DIM * 4);
    float* pooled = (float*)p; p += (size_t)N_GRAPHS * H_DIM * 4;
    float* cnt    = (float*)p; p += align256((size_t)N_GRAPHS * 4);

    // zero accumulators
    hipMemsetAsync(deg, 0, (size_t)N_NODES * 4, stream);
    hipMemsetAsync(agg, 0, (size_t)N_NODES * F_IN * 4, stream);
    hipMemsetAsync(pooled, 0, ((size_t)N_GRAPHS * H_DIM + N_GRAPHS) * 4, stream); // pooled + cnt contiguous

    // combined weights / biases
    addw_kernel<<<(F_IN * H_DIM + 255) / 256, 256, 0, stream>>>(lin_r0_w, res0_w, Wc0, F_IN * H_DIM);
    addw_kernel<<<1, 128, 0, stream>>>(lin_l0_b, res0_b, bc0, H_DIM);
    addw_kernel<<<(H_DIM * H_DIM + 255) / 256, 256, 0, stream>>>(lin_r1_w, res1_w, Wc1, H_DIM * H_DIM);
    addw_kernel<<<1, 128, 0, stream>>>(lin_l1_b, res1_b, bc1, H_DIM);

    deg_kernel<<<(N_EDGES + 255) / 256, 256, 0, stream>>>(dst, deg);

    // layer 0
    scatter_kernel<F_IN><<<(N_EDGES * (F_IN / 4) + 255) / 256, 256, 0, stream>>>(x, src, dst, agg);
    layer_kernel<F_IN, true><<<2048, 64, 0, stream>>>(agg, x, deg, lin_l0_w, Wc0, bc0,
                                                      ln0_g, ln0_b, h0, N_NODES);

    // layer 1
    hipMemsetAsync(agg, 0, (size_t)N_NODES * H_DIM * 4, stream);
    scatter_kernel<H_DIM><<<(N_EDGES * (H_DIM / 4) + 255) / 256, 256, 0, stream>>>(h0, src, dst, agg);
    layer_kernel<H_DIM, false><<<2048, 64, 0, stream>>>(agg, h0, deg, lin_l1_w, Wc1, bc1,
                                                        ln1_g, ln1_b, agg /*in-place h1*/, N_NODES);

    // pool + final
    pool_kernel<<<(N_NODES * 32 + 255) / 256, 256, 0, stream>>>(agg, batch, pooled, cnt);
    final_kernel<<<N_GRAPHS, 64, 0, stream>>>(pooled, cnt, out_w, out_b, out);
}

// Round 2
// 444.327 us; speedup vs baseline: 5.3512x; 5.3512x over previous
//
#include <hip/hip_runtime.h>

#define N_NODES 50000
#define N_EDGES 800000
#define F_IN    64
#define H_DIM   128
#define N_GRAPHS 512
#define LN_EPS  1e-5f
#define CAP     64          // max in-degree bucket capacity (Poisson(16): P(deg>=64) ~ 1e-20)

// ---------------------------------------------------------------------------
// elementwise add (combine Wr + Rres, bl + bres)
__global__ void addw_kernel(const float* __restrict__ a, const float* __restrict__ b,
                            float* __restrict__ o, int n) {
    int i = blockIdx.x * blockDim.x + threadIdx.x;
    if (i < n) o[i] = a[i] + b[i];
}

// ---------------------------------------------------------------------------
// bucket fill: for each edge, append src to dst's bucket. cursor counts true degree.
__global__ void fill_kernel(const int* __restrict__ src, const int* __restrict__ dst,
                            int* __restrict__ cursor, int* __restrict__ bucket) {
    int e = blockIdx.x * blockDim.x + threadIdx.x;
    if (e >= N_EDGES) return;
    int d = dst[e];
    int pos = atomicAdd(&cursor[d], 1);
    if (pos < CAP) bucket[(size_t)d * CAP + pos] = src[e];
}

// ---------------------------------------------------------------------------
// gather-aggregate: agg[n] = sum_{e in bucket[n]} h[src_e]  (sum; mean applied later)
// one wave per node; lane owns K/64 columns; 4-deep unroll for latency hiding.
template <int K>
__launch_bounds__(256)
__global__ void gather_agg_kernel(const float* __restrict__ h, const int* __restrict__ bucket,
                                  const int* __restrict__ degv, float* __restrict__ agg) {
    constexpr int CPL = K / 64;            // columns per lane
    const int wave = (blockIdx.x * blockDim.x + threadIdx.x) >> 6;
    const int lane = threadIdx.x & 63;
    if (wave >= N_NODES) return;
    int dg = degv[wave];
    if (dg > CAP) dg = CAP;
    const int* bk = &bucket[(size_t)wave * CAP];

    float acc[4][CPL];
    #pragma unroll
    for (int u = 0; u < 4; ++u)
        #pragma unroll
        for (int c = 0; c < CPL; ++c) acc[u][c] = 0.f;

    int e = 0;
    for (; e + 4 <= dg; e += 4) {
        int s0 = bk[e], s1 = bk[e + 1], s2 = bk[e + 2], s3 = bk[e + 3];
        #pragma unroll
        for (int c = 0; c < CPL; ++c) {
            acc[0][c] += h[(size_t)s0 * K + c * 64 + lane];
            acc[1][c] += h[(size_t)s1 * K + c * 64 + lane];
            acc[2][c] += h[(size_t)s2 * K + c * 64 + lane];
            acc[3][c] += h[(size_t)s3 * K + c * 64 + lane];
        }
    }
    for (; e < dg; ++e) {
        int s = bk[e];
        #pragma unroll
        for (int c = 0; c < CPL; ++c) acc[0][c] += h[(size_t)s * K + c * 64 + lane];
    }
    #pragma unroll
    for (int c = 0; c < CPL; ++c)
        agg[(size_t)wave * K + c * 64 + lane] = (acc[0][c] + acc[1][c]) + (acc[2][c] + acc[3][c]);
}

// ---------------------------------------------------------------------------
// wave (64-lane) reduction
__device__ __forceinline__ float waveReduceSum(float v) {
    #pragma unroll
    for (int off = 32; off > 0; off >>= 1) v += __shfl_xor(v, off, 64);
    return v;
}

// ---------------------------------------------------------------------------
// fused node update:
//   out = LN( (agg/deg) @ Wl + hin @ Wc + bc ) [*ReLU]
// 1 wave per block; thread handles columns j and j+64; NB=8 nodes per iter.
template <int K, bool RELU>
__launch_bounds__(64)
__global__ void layer_kernel(const float* __restrict__ agg,   // [N,K] (sum, pre-division)
                             const float* __restrict__ hin,   // [N,K]
                             const int*   __restrict__ degv,  // [N]
                             const float* __restrict__ Wl,    // [K,128]
                             const float* __restrict__ Wc,    // [K,128]
                             const float* __restrict__ bc,    // [128]
                             const float* __restrict__ ln_g,  // [128]
                             const float* __restrict__ ln_b,  // [128]
                             float* __restrict__ hout,        // [N,128]
                             int nNodes) {
    constexpr int NB = 8;
    constexpr int K4 = K / 4;
    __shared__ __align__(16) float sAgg[NB][K];
    __shared__ __align__(16) float sX[NB][K];

    const int j = threadIdx.x;           // 0..63
    const int j2 = j + 64;

    const float g0 = ln_g[j],  b0 = ln_b[j];
    const float g1 = ln_g[j2], b1 = ln_b[j2];
    const float bias0 = bc[j], bias1 = bc[j2];

    for (int base = blockIdx.x * NB; base < nNodes; base += gridDim.x * NB) {
        // ---- stage NB rows of agg and hin into LDS (float4) ----
        #pragma unroll
        for (int t = j; t < NB * K4; t += 64) {
            int n = t / K4, c = t % K4;
            *reinterpret_cast<float4*>(&sAgg[n][c * 4]) =
                *reinterpret_cast<const float4*>(&agg[(size_t)(base + n) * K + c * 4]);
            *reinterpret_cast<float4*>(&sX[n][c * 4]) =
                *reinterpret_cast<const float4*>(&hin[(size_t)(base + n) * K + c * 4]);
        }
        __syncthreads();

        // ---- accumulate ----
        float accA0[NB], accA1[NB], accX0[NB], accX1[NB];
        #pragma unroll
        for (int n = 0; n < NB; ++n) { accA0[n] = 0.f; accA1[n] = 0.f; accX0[n] = 0.f; accX1[n] = 0.f; }

        for (int k = 0; k < K; k += 4) {
            float wl0[4], wl1[4], wc0[4], wc1[4];
            #pragma unroll
            for (int u = 0; u < 4; ++u) {
                wl0[u] = Wl[(size_t)(k + u) * H_DIM + j];
                wl1[u] = Wl[(size_t)(k + u) * H_DIM + j2];
                wc0[u] = Wc[(size_t)(k + u) * H_DIM + j];
                wc1[u] = Wc[(size_t)(k + u) * H_DIM + j2];
            }
            #pragma unroll
            for (int n = 0; n < NB; ++n) {
                const float4 ra = *reinterpret_cast<const float4*>(&sAgg[n][k]);
                const float4 rx = *reinterpret_cast<const float4*>(&sX[n][k]);
                accA0[n] = fmaf(ra.x, wl0[0], accA0[n]);
                accA0[n] = fmaf(ra.y, wl0[1], accA0[n]);
                accA0[n] = fmaf(ra.z, wl0[2], accA0[n]);
                accA0[n] = fmaf(ra.w, wl0[3], accA0[n]);
                accA1[n] = fmaf(ra.x, wl1[0], accA1[n]);
                accA1[n] = fmaf(ra.y, wl1[1], accA1[n]);
                accA1[n] = fmaf(ra.z, wl1[2], accA1[n]);
                accA1[n] = fmaf(ra.w, wl1[3], accA1[n]);
                accX0[n] = fmaf(rx.x, wc0[0], accX0[n]);
                accX0[n] = fmaf(rx.y, wc0[1], accX0[n]);
                accX0[n] = fmaf(rx.z, wc0[2], accX0[n]);
                accX0[n] = fmaf(rx.w, wc0[3], accX0[n]);
                accX1[n] = fmaf(rx.x, wc1[0], accX1[n]);
                accX1[n] = fmaf(rx.y, wc1[1], accX1[n]);
                accX1[n] = fmaf(rx.z, wc1[2], accX1[n]);
                accX1[n] = fmaf(rx.w, wc1[3], accX1[n]);
            }
        }

        // ---- finalize: invdeg, LayerNorm (wave-internal), write ----
        #pragma unroll
        for (int n = 0; n < NB; ++n) {
            const float dg = (float)degv[base + n];
            const float invd = 1.0f / fmaxf(dg, 1.0f);
            float v0 = accX0[n] + bias0 + invd * accA0[n];
            float v1 = accX1[n] + bias1 + invd * accA1[n];
            const float sum = waveReduceSum(v0 + v1);
            const float mean = sum * (1.0f / H_DIM);
            const float d0 = v0 - mean, d1 = v1 - mean;
            const float ss = waveReduceSum(d0 * d0 + d1 * d1);
            const float rstd = rsqrtf(ss * (1.0f / H_DIM) + LN_EPS);
            float o0 = d0 * rstd * g0 + b0;
            float o1 = d1 * rstd * g1 + b1;
            if (RELU) { o0 = fmaxf(o0, 0.f); o1 = fmaxf(o1, 0.f); }
            hout[(size_t)(base + n) * H_DIM + j]  = o0;
            hout[(size_t)(base + n) * H_DIM + j2] = o1;
        }
        __syncthreads();
    }
}

// ---------------------------------------------------------------------------
// mean-pool per graph (atomic accumulate)
__global__ void pool_kernel(const float* __restrict__ h, const int* __restrict__ batch,
                            float* __restrict__ pooled, float* __restrict__ cnt) {
    int tid = blockIdx.x * blockDim.x + threadIdx.x;
    int i = tid >> 5;           // node
    int c = tid & 31;           // float4 chunk
    if (i >= N_NODES) return;
    int g = batch[i];
    const float4 v = *reinterpret_cast<const float4*>(&h[(size_t)i * H_DIM + c * 4]);
    float* p = &pooled[(size_t)g * H_DIM + c * 4];
    atomicAdd(p + 0, v.x);
    atomicAdd(p + 1, v.y);
    atomicAdd(p + 2, v.z);
    atomicAdd(p + 3, v.w);
    if (c == 0) atomicAdd(&cnt[g], 1.0f);
}

// ---------------------------------------------------------------------------
// final: out[g] = (pooled[g]/cnt[g]) . out_w + out_b
__global__ void final_kernel(const float* __restrict__ pooled, const float* __restrict__ cnt,
                             const float* __restrict__ ow, const float* __restrict__ ob,
                             float* __restrict__ out) {
    int gph = blockIdx.x;
    int lane = threadIdx.x;
    float s = pooled[(size_t)gph * H_DIM + lane] * ow[lane]
            + pooled[(size_t)gph * H_DIM + 64 + lane] * ow[64 + lane];
    s = waveReduceSum(s);
    if (lane == 0) out[gph] = s / fmaxf(cnt[gph], 1.0f) + ob[0];
}

// ---------------------------------------------------------------------------
static inline size_t align256(size_t x) { return (x + 255) & ~(size_t)255; }

extern "C" void kernel_launch(void* const* d_in, const int* in_sizes, int n_in,
                              void* d_out, int out_size, void* d_ws, size_t ws_size,
                              hipStream_t stream) {
    const float* x        = (const float*)d_in[0];
    const int*   eidx     = (const int*)d_in[1];
    const int*   batch    = (const int*)d_in[2];
    const float* lin_l0_w = (const float*)d_in[3];
    const float* lin_l0_b = (const float*)d_in[4];
    const float* lin_r0_w = (const float*)d_in[5];
    const float* res0_w   = (const float*)d_in[6];
    const float* res0_b   = (const float*)d_in[7];
    const float* ln0_g    = (const float*)d_in[8];
    const float* ln0_b    = (const float*)d_in[9];
    const float* lin_l1_w = (const float*)d_in[10];
    const float* lin_l1_b = (const float*)d_in[11];
    const float* lin_r1_w = (const float*)d_in[12];
    const float* res1_w   = (const float*)d_in[13];
    const float* res1_b   = (const float*)d_in[14];
    const float* ln1_g    = (const float*)d_in[15];
    const float* ln1_b    = (const float*)d_in[16];
    const float* out_w    = (const float*)d_in[17];
    const float* out_b    = (const float*)d_in[18];
    float* out = (float*)d_out;

    const int* src = eidx;
    const int* dst = eidx + N_EDGES;

    // workspace layout
    char* p = (char*)d_ws;
    int*   cursor = (int*)p;   p += align256((size_t)N_NODES * 4);
    int*   bucket = (int*)p;   p += align256((size_t)N_NODES * CAP * 4);
    float* agg    = (float*)p; p += align256((size_t)N_NODES * H_DIM * 4);   // also h1 (in place)
    float* h0     = (float*)p; p += align256((size_t)N_NODES * H_DIM * 4);
    float* Wc0    = (float*)p; p += align256((size_t)F_IN * H_DIM * 4);
    float* bc0    = (float*)p; p += align256((size_t)H_DIM * 4);
    float* Wc1    = (float*)p; p += align256((size_t)H_DIM * H_DIM * 4);
    float* bc1    = (float*)p; p += align256((size_t)H_DIM * 4);
    float* pooled = (float*)p; p += (size_t)N_GRAPHS * H_DIM * 4;
    float* cnt    = (float*)p; p += align256((size_t)N_GRAPHS * 4);

    // zero accumulators
    hipMemsetAsync(cursor, 0, (size_t)N_NODES * 4, stream);
    hipMemsetAsync(pooled, 0, ((size_t)N_GRAPHS * H_DIM + N_GRAPHS) * 4, stream); // pooled + cnt contiguous

    // combined weights / biases
    addw_kernel<<<(F_IN * H_DIM + 255) / 256, 256, 0, stream>>>(lin_r0_w, res0_w, Wc0, F_IN * H_DIM);
    addw_kernel<<<1, 128, 0, stream>>>(lin_l0_b, res0_b, bc0, H_DIM);
    addw_kernel<<<(H_DIM * H_DIM + 255) / 256, 256, 0, stream>>>(lin_r1_w, res1_w, Wc1, H_DIM * H_DIM);
    addw_kernel<<<1, 128, 0, stream>>>(lin_l1_b, res1_b, bc1, H_DIM);

    // bucket edges by destination (replaces atomic scatter)
    fill_kernel<<<(N_EDGES + 255) / 256, 256, 0, stream>>>(src, dst, cursor, bucket);

    // layer 0
    gather_agg_kernel<F_IN><<<(N_NODES * 64 + 255) / 256, 256, 0, stream>>>(x, bucket, cursor, agg);
    layer_kernel<F_IN, true><<<2048, 64, 0, stream>>>(agg, x, cursor, lin_l0_w, Wc0, bc0,
                                                      ln0_g, ln0_b, h0, N_NODES);

    // layer 1
    gather_agg_kernel<H_DIM><<<(N_NODES * 64 + 255) / 256, 256, 0, stream>>>(h0, bucket, cursor, agg);
    layer_kernel<H_DIM, false><<<2048, 64, 0, stream>>>(agg, h0, cursor, lin_l1_w, Wc1, bc1,
                                                        ln1_g, ln1_b, agg /*in-place h1*/, N_NODES);

    // pool + final
    pool_kernel<<<(N_NODES * 32 + 255) / 256, 256, 0, stream>>>(agg, batch, pooled, cnt);
    final_kernel<<<N_GRAPHS, 64, 0, stream>>>(pooled, cnt, out_w, out_b, out);
}

// Round 3
// 293.337 us; speedup vs baseline: 8.1056x; 1.5147x over previous
//
#include <hip/hip_runtime.h>

#define N_NODES 50000
#define N_EDGES 800000
#define F_IN    64
#define H_DIM   128
#define N_GRAPHS 512
#define LN_EPS  1e-5f
#define CAP     64          // max in-degree bucket capacity (Poisson(16): P(deg>=64) ~ 1e-20)

// ---------------------------------------------------------------------------
// elementwise add (combine Wr + Rres, bl + bres)
__global__ void addw_kernel(const float* __restrict__ a, const float* __restrict__ b,
                            float* __restrict__ o, int n) {
    int i = blockIdx.x * blockDim.x + threadIdx.x;
    if (i < n) o[i] = a[i] + b[i];
}

// ---------------------------------------------------------------------------
// bucket fill: for each edge, append src to dst's bucket. cursor counts true degree.
__global__ void fill_kernel(const int* __restrict__ src, const int* __restrict__ dst,
                            int* __restrict__ cursor, int* __restrict__ bucket) {
    int e = blockIdx.x * blockDim.x + threadIdx.x;
    if (e >= N_EDGES) return;
    int d = dst[e];
    int pos = atomicAdd(&cursor[d], 1);
    if (pos < CAP) bucket[(size_t)d * CAP + pos] = src[e];
}

// ---------------------------------------------------------------------------
// graph segment boundaries from the SORTED batch vector: start[g] = first node of graph g
__global__ void bounds_kernel(const int* __restrict__ batch, int* __restrict__ start) {
    int i = blockIdx.x * blockDim.x + threadIdx.x;
    if (i >= N_NODES) return;
    int b = batch[i];
    int prev = (i == 0) ? -1 : batch[i - 1];
    for (int g = prev + 1; g <= b; ++g) start[g] = i;
    if (i == N_NODES - 1)
        for (int g = b + 1; g <= N_GRAPHS; ++g) start[g] = N_NODES;
}

// ---------------------------------------------------------------------------
// gather-aggregate: agg[n] = sum_{e in bucket[n]} h[src_e]  (sum; mean applied later)
// one wave per node; lane owns K/64 columns; 4-deep unroll for latency hiding.
template <int K>
__launch_bounds__(256)
__global__ void gather_agg_kernel(const float* __restrict__ h, const int* __restrict__ bucket,
                                  const int* __restrict__ degv, float* __restrict__ agg) {
    constexpr int CPL = K / 64;            // columns per lane
    const int wave = (blockIdx.x * blockDim.x + threadIdx.x) >> 6;
    const int lane = threadIdx.x & 63;
    if (wave >= N_NODES) return;
    int dg = degv[wave];
    if (dg > CAP) dg = CAP;
    const int* bk = &bucket[(size_t)wave * CAP];

    float acc[4][CPL];
    #pragma unroll
    for (int u = 0; u < 4; ++u)
        #pragma unroll
        for (int c = 0; c < CPL; ++c) acc[u][c] = 0.f;

    int e = 0;
    for (; e + 4 <= dg; e += 4) {
        int s0 = bk[e], s1 = bk[e + 1], s2 = bk[e + 2], s3 = bk[e + 3];
        #pragma unroll
        for (int c = 0; c < CPL; ++c) {
            acc[0][c] += h[(size_t)s0 * K + c * 64 + lane];
            acc[1][c] += h[(size_t)s1 * K + c * 64 + lane];
            acc[2][c] += h[(size_t)s2 * K + c * 64 + lane];
            acc[3][c] += h[(size_t)s3 * K + c * 64 + lane];
        }
    }
    for (; e < dg; ++e) {
        int s = bk[e];
        #pragma unroll
        for (int c = 0; c < CPL; ++c) acc[0][c] += h[(size_t)s * K + c * 64 + lane];
    }
    #pragma unroll
    for (int c = 0; c < CPL; ++c)
        agg[(size_t)wave * K + c * 64 + lane] = (acc[0][c] + acc[1][c]) + (acc[2][c] + acc[3][c]);
}

// ---------------------------------------------------------------------------
// wave (64-lane) reduction
__device__ __forceinline__ float waveReduceSum(float v) {
    #pragma unroll
    for (int off = 32; off > 0; off >>= 1) v += __shfl_xor(v, off, 64);
    return v;
}

// ---------------------------------------------------------------------------
// fused node update:
//   t = LN( (agg/deg) @ Wl + hin @ Wc + bc )
//   FINAL==false: hout[node] = RELU?relu(t):t        (full row)
//   FINAL==true : sOut[node] = t . ow                (per-node scalar for pooling)
// 1 wave per block; thread handles columns j and j+64; NB=8 nodes per iter.
template <int K, bool RELU, bool FINAL>
__launch_bounds__(64)
__global__ void layer_kernel(const float* __restrict__ agg,   // [N,K] (sum, pre-division)
                             const float* __restrict__ hin,   // [N,K]
                             const int*   __restrict__ degv,  // [N]
                             const float* __restrict__ Wl,    // [K,128]
                             const float* __restrict__ Wc,    // [K,128]
                             const float* __restrict__ bc,    // [128]
                             const float* __restrict__ ln_g,  // [128]
                             const float* __restrict__ ln_b,  // [128]
                             const float* __restrict__ ow,    // [128] (FINAL only)
                             float* __restrict__ hout,        // [N,128] or [N] scalar
                             int nNodes) {
    constexpr int NB = 8;
    constexpr int K4 = K / 4;
    __shared__ __align__(16) float sAgg[NB][K];
    __shared__ __align__(16) float sX[NB][K];

    const int j = threadIdx.x;           // 0..63
    const int j2 = j + 64;

    const float g0 = ln_g[j],  b0 = ln_b[j];
    const float g1 = ln_g[j2], b1 = ln_b[j2];
    const float bias0 = bc[j], bias1 = bc[j2];
    float w0 = 0.f, w1 = 0.f;
    if (FINAL) { w0 = ow[j]; w1 = ow[j2]; }

    for (int base = blockIdx.x * NB; base < nNodes; base += gridDim.x * NB) {
        // ---- stage NB rows of agg and hin into LDS (float4) ----
        #pragma unroll
        for (int t = j; t < NB * K4; t += 64) {
            int n = t / K4, c = t % K4;
            *reinterpret_cast<float4*>(&sAgg[n][c * 4]) =
                *reinterpret_cast<const float4*>(&agg[(size_t)(base + n) * K + c * 4]);
            *reinterpret_cast<float4*>(&sX[n][c * 4]) =
                *reinterpret_cast<const float4*>(&hin[(size_t)(base + n) * K + c * 4]);
        }
        __syncthreads();

        // ---- accumulate ----
        float accA0[NB], accA1[NB], accX0[NB], accX1[NB];
        #pragma unroll
        for (int n = 0; n < NB; ++n) { accA0[n] = 0.f; accA1[n] = 0.f; accX0[n] = 0.f; accX1[n] = 0.f; }

        for (int k = 0; k < K; k += 4) {
            float wl0[4], wl1[4], wc0[4], wc1[4];
            #pragma unroll
            for (int u = 0; u < 4; ++u) {
                wl0[u] = Wl[(size_t)(k + u) * H_DIM + j];
                wl1[u] = Wl[(size_t)(k + u) * H_DIM + j2];
                wc0[u] = Wc[(size_t)(k + u) * H_DIM + j];
                wc1[u] = Wc[(size_t)(k + u) * H_DIM + j2];
            }
            #pragma unroll
            for (int n = 0; n < NB; ++n) {
                const float4 ra = *reinterpret_cast<const float4*>(&sAgg[n][k]);
                const float4 rx = *reinterpret_cast<const float4*>(&sX[n][k]);
                accA0[n] = fmaf(ra.x, wl0[0], accA0[n]);
                accA0[n] = fmaf(ra.y, wl0[1], accA0[n]);
                accA0[n] = fmaf(ra.z, wl0[2], accA0[n]);
                accA0[n] = fmaf(ra.w, wl0[3], accA0[n]);
                accA1[n] = fmaf(ra.x, wl1[0], accA1[n]);
                accA1[n] = fmaf(ra.y, wl1[1], accA1[n]);
                accA1[n] = fmaf(ra.z, wl1[2], accA1[n]);
                accA1[n] = fmaf(ra.w, wl1[3], accA1[n]);
                accX0[n] = fmaf(rx.x, wc0[0], accX0[n]);
                accX0[n] = fmaf(rx.y, wc0[1], accX0[n]);
                accX0[n] = fmaf(rx.z, wc0[2], accX0[n]);
                accX0[n] = fmaf(rx.w, wc0[3], accX0[n]);
                accX1[n] = fmaf(rx.x, wc1[0], accX1[n]);
                accX1[n] = fmaf(rx.y, wc1[1], accX1[n]);
                accX1[n] = fmaf(rx.z, wc1[2], accX1[n]);
                accX1[n] = fmaf(rx.w, wc1[3], accX1[n]);
            }
        }

        // ---- finalize: invdeg, LayerNorm (wave-internal), write ----
        #pragma unroll
        for (int n = 0; n < NB; ++n) {
            const float dg = (float)degv[base + n];
            const float invd = 1.0f / fmaxf(dg, 1.0f);
            float v0 = accX0[n] + bias0 + invd * accA0[n];
            float v1 = accX1[n] + bias1 + invd * accA1[n];
            const float sum = waveReduceSum(v0 + v1);
            const float mean = sum * (1.0f / H_DIM);
            const float d0 = v0 - mean, d1 = v1 - mean;
            const float ss = waveReduceSum(d0 * d0 + d1 * d1);
            const float rstd = rsqrtf(ss * (1.0f / H_DIM) + LN_EPS);
            float o0 = d0 * rstd * g0 + b0;
            float o1 = d1 * rstd * g1 + b1;
            if (RELU) { o0 = fmaxf(o0, 0.f); o1 = fmaxf(o1, 0.f); }
            if (FINAL) {
                const float dot = waveReduceSum(o0 * w0 + o1 * w1);
                if (j == 0) hout[base + n] = dot;
            } else {
                hout[(size_t)(base + n) * H_DIM + j]  = o0;
                hout[(size_t)(base + n) * H_DIM + j2] = o1;
            }
        }
        __syncthreads();
    }
}

// ---------------------------------------------------------------------------
// per-graph mean over contiguous node range (batch sorted), plus out_b
__global__ void graph_mean_kernel(const float* __restrict__ s, const int* __restrict__ start,
                                  const float* __restrict__ ob, float* __restrict__ out) {
    const int g = blockIdx.x;
    const int lane = threadIdx.x;
    const int a = start[g], b = start[g + 1];
    float sum = 0.f;
    for (int i = a + lane; i < b; i += 64) sum += s[i];
    sum = waveReduceSum(sum);
    if (lane == 0) out[g] = sum / fmaxf((float)(b - a), 1.0f) + ob[0];
}

// ---------------------------------------------------------------------------
static inline size_t align256(size_t x) { return (x + 255) & ~(size_t)255; }

extern "C" void kernel_launch(void* const* d_in, const int* in_sizes, int n_in,
                              void* d_out, int out_size, void* d_ws, size_t ws_size,
                              hipStream_t stream) {
    const float* x        = (const float*)d_in[0];
    const int*   eidx     = (const int*)d_in[1];
    const int*   batch    = (const int*)d_in[2];
    const float* lin_l0_w = (const float*)d_in[3];
    const float* lin_l0_b = (const float*)d_in[4];
    const float* lin_r0_w = (const float*)d_in[5];
    const float* res0_w   = (const float*)d_in[6];
    const float* res0_b   = (const float*)d_in[7];
    const float* ln0_g    = (const float*)d_in[8];
    const float* ln0_b    = (const float*)d_in[9];
    const float* lin_l1_w = (const float*)d_in[10];
    const float* lin_l1_b = (const float*)d_in[11];
    const float* lin_r1_w = (const float*)d_in[12];
    const float* res1_w   = (const float*)d_in[13];
    const float* res1_b   = (const float*)d_in[14];
    const float* ln1_g    = (const float*)d_in[15];
    const float* ln1_b    = (const float*)d_in[16];
    const float* out_w    = (const float*)d_in[17];
    const float* out_b    = (const float*)d_in[18];
    float* out = (float*)d_out;

    const int* src = eidx;
    const int* dst = eidx + N_EDGES;

    // workspace layout
    char* p = (char*)d_ws;
    int*   cursor = (int*)p;   p += align256((size_t)N_NODES * 4);
    int*   bucket = (int*)p;   p += align256((size_t)N_NODES * CAP * 4);
    int*   gstart = (int*)p;   p += align256((size_t)(N_GRAPHS + 1) * 4);
    float* agg    = (float*)p; p += align256((size_t)N_NODES * H_DIM * 4);
    float* h0     = (float*)p; p += align256((size_t)N_NODES * H_DIM * 4);
    float* snode  = (float*)p; p += align256((size_t)N_NODES * 4);
    float* Wc0    = (float*)p; p += align256((size_t)F_IN * H_DIM * 4);
    float* bc0    = (float*)p; p += align256((size_t)H_DIM * 4);
    float* Wc1    = (float*)p; p += align256((size_t)H_DIM * H_DIM * 4);
    float* bc1    = (float*)p; p += align256((size_t)H_DIM * 4);

    hipMemsetAsync(cursor, 0, (size_t)N_NODES * 4, stream);

    // combined weights / biases
    addw_kernel<<<(F_IN * H_DIM + 255) / 256, 256, 0, stream>>>(lin_r0_w, res0_w, Wc0, F_IN * H_DIM);
    addw_kernel<<<1, 128, 0, stream>>>(lin_l0_b, res0_b, bc0, H_DIM);
    addw_kernel<<<(H_DIM * H_DIM + 255) / 256, 256, 0, stream>>>(lin_r1_w, res1_w, Wc1, H_DIM * H_DIM);
    addw_kernel<<<1, 128, 0, stream>>>(lin_l1_b, res1_b, bc1, H_DIM);

    // bucket edges by destination (replaces atomic scatter) + graph boundaries
    fill_kernel<<<(N_EDGES + 255) / 256, 256, 0, stream>>>(src, dst, cursor, bucket);
    bounds_kernel<<<(N_NODES + 255) / 256, 256, 0, stream>>>(batch, gstart);

    // layer 0
    gather_agg_kernel<F_IN><<<(N_NODES * 64 + 255) / 256, 256, 0, stream>>>(x, bucket, cursor, agg);
    layer_kernel<F_IN, true, false><<<2048, 64, 0, stream>>>(agg, x, cursor, lin_l0_w, Wc0, bc0,
                                                             ln0_g, ln0_b, nullptr, h0, N_NODES);

    // layer 1 (fused with out_w dot product -> per-node scalar)
    gather_agg_kernel<H_DIM><<<(N_NODES * 64 + 255) / 256, 256, 0, stream>>>(h0, bucket, cursor, agg);
    layer_kernel<H_DIM, false, true><<<2048, 64, 0, stream>>>(agg, h0, cursor, lin_l1_w, Wc1, bc1,
                                                              ln1_g, ln1_b, out_w, snode, N_NODES);

    // per-graph mean + bias
    graph_mean_kernel<<<N_GRAPHS, 64, 0, stream>>>(snode, gstart, out_b, out);
}

// Round 4
// 172.518 us; speedup vs baseline: 13.7821x; 1.7003x over previous
//
#include <hip/hip_runtime.h>

#define N_NODES 50000
#define N_EDGES 800000
#define F_IN    64
#define H_DIM   128
#define N_GRAPHS 512
#define LN_EPS  1e-5f
#define CAP     64          // max in-degree bucket capacity (Poisson(16): P(deg>=64) ~ 1e-20)

typedef short  short8 __attribute__((ext_vector_type(8)));
typedef float  f32x4  __attribute__((ext_vector_type(4)));
typedef unsigned short u16;
typedef unsigned int   u32;

__device__ __forceinline__ float bf2f(u16 u) {
    u32 b = ((u32)u) << 16;
    return __builtin_bit_cast(float, b);
}
__device__ __forceinline__ u16 f2bf(float f) {   // round-to-nearest-even
    u32 b = __builtin_bit_cast(u32, f);
    return (u16)((b + 0x7FFFu + ((b >> 16) & 1u)) >> 16);
}

// ---------------------------------------------------------------------------
// fp32 -> bf16 bulk convert (4 elems/thread)
__global__ void cvt_kernel(const float* __restrict__ in, u16* __restrict__ out, int n4) {
    int i = blockIdx.x * blockDim.x + threadIdx.x;
    if (i >= n4) return;
    float4 v = reinterpret_cast<const float4*>(in)[i];
    ushort4 o;
    o.x = f2bf(v.x); o.y = f2bf(v.y); o.z = f2bf(v.z); o.w = f2bf(v.w);
    reinterpret_cast<ushort4*>(out)[i] = o;
}

// ---------------------------------------------------------------------------
// combine biases
__global__ void addw_kernel(const float* __restrict__ a, const float* __restrict__ b,
                            float* __restrict__ o, int n) {
    int i = blockIdx.x * blockDim.x + threadIdx.x;
    if (i < n) o[i] = a[i] + b[i];
}

// ---------------------------------------------------------------------------
// pack weights into MFMA B-fragment order, bf16.
// Logical W' [2K x 128]: rows 0..K-1 = Wl, rows K..2K-1 = Wr + Rw.
// out[(kstep*8 + tile)*64 + lane] holds 8 bf16: k = kstep*32 + (lane>>4)*8 + e,
// col = tile*16 + (lane&15).
__global__ void packw_kernel(const float* __restrict__ Wl, const float* __restrict__ Wr,
                             const float* __restrict__ Rw, u16* __restrict__ out, int K) {
    int tid = blockIdx.x * blockDim.x + threadIdx.x;
    int total = ((2 * K) / 32) * 8 * 64;
    if (tid >= total) return;
    int lane = tid & 63;
    int tile = (tid >> 6) & 7;
    int kstep = tid >> 9;
    int col = tile * 16 + (lane & 15);
    short8 o;
    #pragma unroll
    for (int e = 0; e < 8; ++e) {
        int k = kstep * 32 + (lane >> 4) * 8 + e;
        float v = (k < K) ? Wl[(size_t)k * H_DIM + col]
                          : (Wr[(size_t)(k - K) * H_DIM + col] + Rw[(size_t)(k - K) * H_DIM + col]);
        o[e] = (short)f2bf(v);
    }
    *reinterpret_cast<short8*>(&out[(size_t)tid * 8]) = o;
}

// ---------------------------------------------------------------------------
// bucket fill: append src to dst's bucket; cursor = true in-degree
__global__ void fill_kernel(const int* __restrict__ src, const int* __restrict__ dst,
                            int* __restrict__ cursor, int* __restrict__ bucket) {
    int e = blockIdx.x * blockDim.x + threadIdx.x;
    if (e >= N_EDGES) return;
    int d = dst[e];
    int pos = atomicAdd(&cursor[d], 1);
    if (pos < CAP) bucket[(size_t)d * CAP + pos] = src[e];
}

// ---------------------------------------------------------------------------
// graph boundaries from sorted batch
__global__ void bounds_kernel(const int* __restrict__ batch, int* __restrict__ start) {
    int i = blockIdx.x * blockDim.x + threadIdx.x;
    if (i >= N_NODES) return;
    int b = batch[i];
    int prev = (i == 0) ? -1 : batch[i - 1];
    for (int g = prev + 1; g <= b; ++g) start[g] = i;
    if (i == N_NODES - 1)
        for (int g = b + 1; g <= N_GRAPHS; ++g) start[g] = N_NODES;
}

// ---------------------------------------------------------------------------
// gather-aggregate (bf16 in, bf16 out, fp32 accumulate, mean applied here)
template <int K>
__launch_bounds__(256)
__global__ void gather_kernel(const u16* __restrict__ h, const int* __restrict__ bucket,
                              const int* __restrict__ degv, u16* __restrict__ agg) {
    constexpr int CL = K / 64;       // cols per lane: 1 (K=64) or 2 (K=128)
    const int node = (blockIdx.x * blockDim.x + threadIdx.x) >> 6;
    const int lane = threadIdx.x & 63;
    if (node >= N_NODES) return;
    int dg = degv[node];
    int dgc = dg > CAP ? CAP : dg;
    const int* bk = &bucket[(size_t)node * CAP];

    float a0[4] = {0.f, 0.f, 0.f, 0.f};
    float a1[4] = {0.f, 0.f, 0.f, 0.f};

    int e = 0;
    for (; e + 4 <= dgc; e += 4) {
        int s0 = bk[e], s1 = bk[e + 1], s2 = bk[e + 2], s3 = bk[e + 3];
        if constexpr (CL == 2) {
            u32 u0 = *reinterpret_cast<const u32*>(&h[(size_t)s0 * K + lane * 2]);
            u32 u1 = *reinterpret_cast<const u32*>(&h[(size_t)s1 * K + lane * 2]);
            u32 u2 = *reinterpret_cast<const u32*>(&h[(size_t)s2 * K + lane * 2]);
            u32 u3 = *reinterpret_cast<const u32*>(&h[(size_t)s3 * K + lane * 2]);
            a0[0] += bf2f((u16)u0); a1[0] += bf2f((u16)(u0 >> 16));
            a0[1] += bf2f((u16)u1); a1[1] += bf2f((u16)(u1 >> 16));
            a0[2] += bf2f((u16)u2); a1[2] += bf2f((u16)(u2 >> 16));
            a0[3] += bf2f((u16)u3); a1[3] += bf2f((u16)(u3 >> 16));
        } else {
            a0[0] += bf2f(h[(size_t)s0 * K + lane]);
            a0[1] += bf2f(h[(size_t)s1 * K + lane]);
            a0[2] += bf2f(h[(size_t)s2 * K + lane]);
            a0[3] += bf2f(h[(size_t)s3 * K + lane]);
        }
    }
    for (; e < dgc; ++e) {
        int s = bk[e];
        if constexpr (CL == 2) {
            u32 u = *reinterpret_cast<const u32*>(&h[(size_t)s * K + lane * 2]);
            a0[0] += bf2f((u16)u); a1[0] += bf2f((u16)(u >> 16));
        } else {
            a0[0] += bf2f(h[(size_t)s * K + lane]);
        }
    }
    const float invd = 1.0f / fmaxf((float)dg, 1.0f);
    const float s0 = ((a0[0] + a0[1]) + (a0[2] + a0[3])) * invd;
    if constexpr (CL == 2) {
        const float s1 = ((a1[0] + a1[1]) + (a1[2] + a1[3])) * invd;
        u32 o = (u32)f2bf(s0) | ((u32)f2bf(s1) << 16);
        *reinterpret_cast<u32*>(&agg[(size_t)node * K + lane * 2]) = o;
    } else {
        agg[(size_t)node * K + lane] = f2bf(s0);
    }
}

// ---------------------------------------------------------------------------
// fused MFMA layer: pre = [agg | hin] @ [Wl ; Wc] + bc ; t = LN(pre)
//   FINAL=false: hout = (RELU ? relu(t) : t) as bf16 [N,128]
//   FINAL=true : sout[node] = t . ow  (fp32 scalar)
// Block = 256 threads (4 waves), 64-row tile; wave w owns rows w*16..w*16+15.
// A tile staged in LDS row-major with XOR swizzle (byte ^= (row&7)<<4).
template <int K, bool RELU, bool FINAL>
__launch_bounds__(256)
__global__ void layer_mfma_kernel(const u16* __restrict__ aggbf,   // [N,K] (invd applied)
                                  const u16* __restrict__ hbf,     // [N,K]
                                  const u16* __restrict__ Wpack,   // fragment-ordered
                                  const float* __restrict__ bc,    // [128]
                                  const float* __restrict__ ln_g,  // [128]
                                  const float* __restrict__ ln_b,  // [128]
                                  const float* __restrict__ ow,    // [128] (FINAL)
                                  u16* __restrict__ hout,          // [N,128] (non-FINAL)
                                  float* __restrict__ sout) {      // [N]     (FINAL)
    constexpr int K2   = 2 * K;
    constexpr int NKS  = K2 / 32;     // MFMA k-steps
    constexpr int ROWB = K2 * 2;      // bytes per LDS row
    constexpr int CPR  = ROWB / 16;   // 16B chunks per row
    __shared__ __align__(16) char sA[64 * ROWB];

    const int tid  = threadIdx.x;
    const int lane = tid & 63;
    const int wid  = tid >> 6;
    const int base = blockIdx.x * 64;

    // ---- stage A tile (cols 0..K-1 = agg, K..2K-1 = hin), coalesced 16B ----
    for (int c = tid; c < 64 * CPR; c += 256) {
        int row = c / CPR, c16 = c % CPR;
        int rg = base + row; if (rg >= N_NODES) rg = N_NODES - 1;
        const u16* srcp = (c16 < CPR / 2) ? &aggbf[(size_t)rg * K + c16 * 8]
                                          : &hbf[(size_t)rg * K + (c16 - CPR / 2) * 8];
        float4 v = *reinterpret_cast<const float4*>(srcp);
        *reinterpret_cast<float4*>(&sA[row * ROWB + ((c16 * 16) ^ ((row & 7) << 4))]) = v;
    }
    __syncthreads();

    // ---- MFMA accumulate: 8 col-tiles of 16, rows = wave's 16 ----
    f32x4 acc[8];
    #pragma unroll
    for (int t = 0; t < 8; ++t) acc[t] = (f32x4){0.f, 0.f, 0.f, 0.f};

    const int arow = lane & 15;
    const int kg   = lane >> 4;
    const int lrow = wid * 16 + arow;               // LDS row
    #pragma unroll
    for (int ks = 0; ks < NKS; ++ks) {
        short8 af = *reinterpret_cast<const short8*>(
            &sA[lrow * ROWB + (((ks * 64 + kg * 16)) ^ ((lrow & 7) << 4))]);
        #pragma unroll
        for (int t = 0; t < 8; ++t) {
            short8 bf = *reinterpret_cast<const short8*>(&Wpack[(size_t)((ks * 8 + t) * 64 + lane) * 8]);
            acc[t] = __builtin_amdgcn_mfma_f32_16x16x32_bf16(af, bf, acc[t], 0, 0, 0);
        }
    }

    // ---- epilogue: +bias, LayerNorm per row (16-lane reduce), output ----
    // C layout: col = (lane&15) + 16*t ; row = wid*16 + (lane>>4)*4 + reg
    const int col0 = lane & 15;
    const int g    = lane >> 4;

    float lg[8], lb[8], wv[8];
    #pragma unroll
    for (int t = 0; t < 8; ++t) {
        const int col = col0 + 16 * t;
        const float cb = bc[col];
        lg[t] = ln_g[col]; lb[t] = ln_b[col];
        if (FINAL) wv[t] = ow[col];
        #pragma unroll
        for (int r = 0; r < 4; ++r) acc[t][r] += cb;
    }

    #pragma unroll
    for (int r = 0; r < 4; ++r) {
        float s = 0.f, q = 0.f;
        #pragma unroll
        for (int t = 0; t < 8; ++t) { s += acc[t][r]; q += acc[t][r] * acc[t][r]; }
        #pragma unroll
        for (int off = 8; off > 0; off >>= 1) {
            s += __shfl_xor(s, off, 64);
            q += __shfl_xor(q, off, 64);
        }
        const float mean = s * (1.0f / H_DIM);
        const float var  = q * (1.0f / H_DIM) - mean * mean;
        const float rstd = rsqrtf(var + LN_EPS);
        const int row = base + wid * 16 + g * 4 + r;

        if (FINAL) {
            float dot = 0.f;
            #pragma unroll
            for (int t = 0; t < 8; ++t) {
                float o = (acc[t][r] - mean) * rstd * lg[t] + lb[t];
                dot += o * wv[t];
            }
            #pragma unroll
            for (int off = 8; off > 0; off >>= 1) dot += __shfl_xor(dot, off, 64);
            if (col0 == 0 && row < N_NODES) sout[row] = dot;
        } else {
            if (row < N_NODES) {
                #pragma unroll
                for (int t = 0; t < 8; ++t) {
                    float o = (acc[t][r] - mean) * rstd * lg[t] + lb[t];
                    if (RELU) o = fmaxf(o, 0.f);
                    hout[(size_t)row * H_DIM + col0 + 16 * t] = f2bf(o);
                }
            }
        }
    }
}

// ---------------------------------------------------------------------------
__device__ __forceinline__ float waveReduceSum(float v) {
    #pragma unroll
    for (int off = 32; off > 0; off >>= 1) v += __shfl_xor(v, off, 64);
    return v;
}

// per-graph mean over contiguous node range (batch sorted), plus out_b
__global__ void graph_mean_kernel(const float* __restrict__ s, const int* __restrict__ start,
                                  const float* __restrict__ ob, float* __restrict__ out) {
    const int g = blockIdx.x;
    const int lane = threadIdx.x;
    const int a = start[g], b = start[g + 1];
    float sum = 0.f;
    for (int i = a + lane; i < b; i += 64) sum += s[i];
    sum = waveReduceSum(sum);
    if (lane == 0) out[g] = sum / fmaxf((float)(b - a), 1.0f) + ob[0];
}

// ---------------------------------------------------------------------------
static inline size_t align256(size_t x) { return (x + 255) & ~(size_t)255; }

extern "C" void kernel_launch(void* const* d_in, const int* in_sizes, int n_in,
                              void* d_out, int out_size, void* d_ws, size_t ws_size,
                              hipStream_t stream) {
    const float* x        = (const float*)d_in[0];
    const int*   eidx     = (const int*)d_in[1];
    const int*   batch    = (const int*)d_in[2];
    const float* lin_l0_w = (const float*)d_in[3];
    const float* lin_l0_b = (const float*)d_in[4];
    const float* lin_r0_w = (const float*)d_in[5];
    const float* res0_w   = (const float*)d_in[6];
    const float* res0_b   = (const float*)d_in[7];
    const float* ln0_g    = (const float*)d_in[8];
    const float* ln0_b    = (const float*)d_in[9];
    const float* lin_l1_w = (const float*)d_in[10];
    const float* lin_l1_b = (const float*)d_in[11];
    const float* lin_r1_w = (const float*)d_in[12];
    const float* res1_w   = (const float*)d_in[13];
    const float* res1_b   = (const float*)d_in[14];
    const float* ln1_g    = (const float*)d_in[15];
    const float* ln1_b    = (const float*)d_in[16];
    const float* out_w    = (const float*)d_in[17];
    const float* out_b    = (const float*)d_in[18];
    float* out = (float*)d_out;

    const int* src = eidx;
    const int* dst = eidx + N_EDGES;

    // workspace layout
    char* p = (char*)d_ws;
    int*   cursor = (int*)p;  p += align256((size_t)N_NODES * 4);
    int*   bucket = (int*)p;  p += align256((size_t)N_NODES * CAP * 4);
    int*   gstart = (int*)p;  p += align256((size_t)(N_GRAPHS + 1) * 4);
    u16*   xbf    = (u16*)p;  p += align256((size_t)N_NODES * F_IN * 2);
    u16*   h0bf   = (u16*)p;  p += align256((size_t)N_NODES * H_DIM * 2);
    u16*   aggbf  = (u16*)p;  p += align256((size_t)N_NODES * H_DIM * 2);
    float* snode  = (float*)p; p += align256((size_t)N_NODES * 4);
    u16*   W0p    = (u16*)p;  p += align256((size_t)(2 * F_IN) * H_DIM * 2);
    u16*   W1p    = (u16*)p;  p += align256((size_t)(2 * H_DIM) * H_DIM * 2);
    float* bc0    = (float*)p; p += align256((size_t)H_DIM * 4);
    float* bc1    = (float*)p; p += align256((size_t)H_DIM * 4);

    hipMemsetAsync(cursor, 0, (size_t)N_NODES * 4, stream);

    // convert x to bf16; combine biases; pack weights
    cvt_kernel<<<(N_NODES * F_IN / 4 + 255) / 256, 256, 0, stream>>>(x, xbf, N_NODES * F_IN / 4);
    addw_kernel<<<1, 128, 0, stream>>>(lin_l0_b, res0_b, bc0, H_DIM);
    addw_kernel<<<1, 128, 0, stream>>>(lin_l1_b, res1_b, bc1, H_DIM);
    packw_kernel<<<(2048 + 255) / 256, 256, 0, stream>>>(lin_l0_w, lin_r0_w, res0_w, W0p, F_IN);
    packw_kernel<<<(4096 + 255) / 256, 256, 0, stream>>>(lin_l1_w, lin_r1_w, res1_w, W1p, H_DIM);

    // bucket edges by destination + graph boundaries
    fill_kernel<<<(N_EDGES + 255) / 256, 256, 0, stream>>>(src, dst, cursor, bucket);
    bounds_kernel<<<(N_NODES + 255) / 256, 256, 0, stream>>>(batch, gstart);

    const int nTiles = (N_NODES + 63) / 64;

    // layer 0
    gather_kernel<F_IN><<<(N_NODES * 64 + 255) / 256, 256, 0, stream>>>(xbf, bucket, cursor, aggbf);
    layer_mfma_kernel<F_IN, true, false><<<nTiles, 256, 0, stream>>>(
        aggbf, xbf, W0p, bc0, ln0_g, ln0_b, nullptr, h0bf, nullptr);

    // layer 1 (fused with out_w dot -> per-node scalar)
    gather_kernel<H_DIM><<<(N_NODES * 64 + 255) / 256, 256, 0, stream>>>(h0bf, bucket, cursor, aggbf);
    layer_mfma_kernel<H_DIM, false, true><<<nTiles, 256, 0, stream>>>(
        aggbf, h0bf, W1p, bc1, ln1_g, ln1_b, out_w, nullptr, snode);

    // per-graph mean + bias
    graph_mean_kernel<<<N_GRAPHS, 64, 0, stream>>>(snode, gstart, out_b, out);
}

// Round 5
// 146.111 us; speedup vs baseline: 16.2729x; 1.1807x over previous
//
#include <hip/hip_runtime.h>

#define N_NODES 50000
#define N_EDGES 800000
#define F_IN    64
#define H_DIM   128
#define N_GRAPHS 512
#define LN_EPS  1e-5f
#define CAP     64          // max in-degree bucket capacity (Poisson(16): P(deg>=64) ~ 1e-20)
#define NBINS   196         // ceil(50000/256) -- bin = dst >> 8
#define BINCAP  5120        // edges per bin region (E[bin]=4096, 16 sigma headroom)
#define CHUNK   4096        // edges per partition block

typedef short  short8 __attribute__((ext_vector_type(8)));
typedef float  f32x4  __attribute__((ext_vector_type(4)));
typedef unsigned short u16;
typedef unsigned int   u32;

__device__ __forceinline__ float bf2f(u16 u) {
    u32 b = ((u32)u) << 16;
    return __builtin_bit_cast(float, b);
}
__device__ __forceinline__ u16 f2bf(float f) {   // round-to-nearest-even
    u32 b = __builtin_bit_cast(u32, f);
    return (u16)((b + 0x7FFFu + ((b >> 16) & 1u)) >> 16);
}

// ---------------------------------------------------------------------------
// fp32 -> bf16 bulk convert (4 elems/thread)
__global__ void cvt_kernel(const float* __restrict__ in, u16* __restrict__ out, int n4) {
    int i = blockIdx.x * blockDim.x + threadIdx.x;
    if (i >= n4) return;
    float4 v = reinterpret_cast<const float4*>(in)[i];
    ushort4 o;
    o.x = f2bf(v.x); o.y = f2bf(v.y); o.z = f2bf(v.z); o.w = f2bf(v.w);
    reinterpret_cast<ushort4*>(out)[i] = o;
}

// ---------------------------------------------------------------------------
// combine both layer biases in one launch: o[0:128]=l0+r0, o[128:256]=l1+r1
__global__ void bias_kernel(const float* __restrict__ a0, const float* __restrict__ b0,
                            const float* __restrict__ a1, const float* __restrict__ b1,
                            float* __restrict__ o) {
    int i = threadIdx.x;   // 128
    o[i]       = a0[i] + b0[i];
    o[128 + i] = a1[i] + b1[i];
}

// ---------------------------------------------------------------------------
// pack weights into MFMA B-fragment order, bf16.
// Logical W' [2K x 128]: rows 0..K-1 = Wl, rows K..2K-1 = Wr + Rw.
__global__ void packw_kernel(const float* __restrict__ Wl, const float* __restrict__ Wr,
                             const float* __restrict__ Rw, u16* __restrict__ out, int K) {
    int tid = blockIdx.x * blockDim.x + threadIdx.x;
    int total = ((2 * K) / 32) * 8 * 64;
    if (tid >= total) return;
    int lane = tid & 63;
    int tile = (tid >> 6) & 7;
    int kstep = tid >> 9;
    int col = tile * 16 + (lane & 15);
    short8 o;
    #pragma unroll
    for (int e = 0; e < 8; ++e) {
        int k = kstep * 32 + (lane >> 4) * 8 + e;
        float v = (k < K) ? Wl[(size_t)k * H_DIM + col]
                          : (Wr[(size_t)(k - K) * H_DIM + col] + Rw[(size_t)(k - K) * H_DIM + col]);
        o[e] = (short)f2bf(v);
    }
    *reinterpret_cast<short8*>(&out[(size_t)tid * 8]) = o;
}

// ---------------------------------------------------------------------------
// Phase 1: partition edges into NBINS coarse bins (bin = dst>>8), coalesced runs.
__launch_bounds__(256)
__global__ void partition_kernel(const int* __restrict__ src, const int* __restrict__ dst,
                                 int* __restrict__ binCnt, int2* __restrict__ binned) {
    __shared__ int2 lbuf[CHUNK];
    __shared__ int sHist[256];
    __shared__ int sScan[256];
    __shared__ int sCur[256];
    __shared__ int sGBase[256];
    const int tid = threadIdx.x;
    const int base = blockIdx.x * CHUNK;
    const int cnt = min(CHUNK, N_EDGES - base);

    // load up to 16 edges/thread into registers (coalesced)
    int2 ed[16];
    int nb[16];
    #pragma unroll
    for (int i = 0; i < 16; ++i) {
        int idx = base + i * 256 + tid;
        if (idx < N_EDGES) { ed[i].x = src[idx]; ed[i].y = dst[idx]; nb[i] = ed[i].y >> 8; }
        else nb[i] = -1;
    }
    sHist[tid] = 0;
    __syncthreads();
    #pragma unroll
    for (int i = 0; i < 16; ++i) if (nb[i] >= 0) atomicAdd(&sHist[nb[i]], 1);
    __syncthreads();

    // inclusive Hillis-Steele scan over 256
    sScan[tid] = sHist[tid];
    __syncthreads();
    for (int off = 1; off < 256; off <<= 1) {
        int v = sScan[tid];
        int add = (tid >= off) ? sScan[tid - off] : 0;
        __syncthreads();
        sScan[tid] = v + add;
        __syncthreads();
    }
    int excl = sScan[tid] - sHist[tid];
    __syncthreads();
    sScan[tid] = excl;           // exclusive scan, kept for copy-out
    sCur[tid]  = excl;           // atomic cursor for LDS reorder
    if (tid < NBINS && sHist[tid] > 0)
        sGBase[tid] = atomicAdd(&binCnt[tid], sHist[tid]);   // reserve global range
    __syncthreads();

    // reorder chunk into LDS, grouped by bin
    #pragma unroll
    for (int i = 0; i < 16; ++i) {
        if (nb[i] >= 0) {
            int p = atomicAdd(&sCur[nb[i]], 1);
            lbuf[p] = ed[i];
        }
    }
    __syncthreads();

    // copy out: consecutive t within a bin-run -> consecutive global slots
    for (int t = tid; t < cnt; t += 256) {
        int2 e = lbuf[t];
        int b = e.y >> 8;
        int slot = sGBase[b] + (t - sScan[b]);
        if (slot < BINCAP) binned[(size_t)b * BINCAP + slot] = e;
    }
}

// ---------------------------------------------------------------------------
// Phase 2: per-bin bucket fill; per-node cursors in LDS, bucket region L2-hot.
__launch_bounds__(256)
__global__ void fillbin_kernel(const int2* __restrict__ binned, const int* __restrict__ binCnt,
                               int* __restrict__ bucket, int* __restrict__ degv) {
    __shared__ int lcur[256];
    const int b = blockIdx.x;
    const int tid = threadIdx.x;
    const int nodeBase = b << 8;
    lcur[tid] = 0;
    __syncthreads();
    int cnt = binCnt[b];
    if (cnt > BINCAP) cnt = BINCAP;
    const int2* be = &binned[(size_t)b * BINCAP];
    for (int t = tid; t < cnt; t += 256) {
        int2 e = be[t];
        int pos = atomicAdd(&lcur[e.y & 255], 1);
        if (pos < CAP) bucket[(size_t)e.y * CAP + pos] = e.x;
    }
    __syncthreads();
    int node = nodeBase + tid;
    if (node < N_NODES) degv[node] = lcur[tid];
}

// ---------------------------------------------------------------------------
// graph boundaries from sorted batch
__global__ void bounds_kernel(const int* __restrict__ batch, int* __restrict__ start) {
    int i = blockIdx.x * blockDim.x + threadIdx.x;
    if (i >= N_NODES) return;
    int b = batch[i];
    int prev = (i == 0) ? -1 : batch[i - 1];
    for (int g = prev + 1; g <= b; ++g) start[g] = i;
    if (i == N_NODES - 1)
        for (int g = b + 1; g <= N_GRAPHS; ++g) start[g] = N_NODES;
}

// ---------------------------------------------------------------------------
// gather-aggregate (bf16 in, bf16 out, fp32 accumulate, mean applied here)
template <int K>
__launch_bounds__(256)
__global__ void gather_kernel(const u16* __restrict__ h, const int* __restrict__ bucket,
                              const int* __restrict__ degv, u16* __restrict__ agg) {
    constexpr int CL = K / 64;       // cols per lane: 1 (K=64) or 2 (K=128)
    const int node = (blockIdx.x * blockDim.x + threadIdx.x) >> 6;
    const int lane = threadIdx.x & 63;
    if (node >= N_NODES) return;
    int dg = degv[node];
    int dgc = dg > CAP ? CAP : dg;
    const int* bk = &bucket[(size_t)node * CAP];

    float a0[4] = {0.f, 0.f, 0.f, 0.f};
    float a1[4] = {0.f, 0.f, 0.f, 0.f};

    int e = 0;
    for (; e + 4 <= dgc; e += 4) {
        int s0 = bk[e], s1 = bk[e + 1], s2 = bk[e + 2], s3 = bk[e + 3];
        if constexpr (CL == 2) {
            u32 u0 = *reinterpret_cast<const u32*>(&h[(size_t)s0 * K + lane * 2]);
            u32 u1 = *reinterpret_cast<const u32*>(&h[(size_t)s1 * K + lane * 2]);
            u32 u2 = *reinterpret_cast<const u32*>(&h[(size_t)s2 * K + lane * 2]);
            u32 u3 = *reinterpret_cast<const u32*>(&h[(size_t)s3 * K + lane * 2]);
            a0[0] += bf2f((u16)u0); a1[0] += bf2f((u16)(u0 >> 16));
            a0[1] += bf2f((u16)u1); a1[1] += bf2f((u16)(u1 >> 16));
            a0[2] += bf2f((u16)u2); a1[2] += bf2f((u16)(u2 >> 16));
            a0[3] += bf2f((u16)u3); a1[3] += bf2f((u16)(u3 >> 16));
        } else {
            a0[0] += bf2f(h[(size_t)s0 * K + lane]);
            a0[1] += bf2f(h[(size_t)s1 * K + lane]);
            a0[2] += bf2f(h[(size_t)s2 * K + lane]);
            a0[3] += bf2f(h[(size_t)s3 * K + lane]);
        }
    }
    for (; e < dgc; ++e) {
        int s = bk[e];
        if constexpr (CL == 2) {
            u32 u = *reinterpret_cast<const u32*>(&h[(size_t)s * K + lane * 2]);
            a0[0] += bf2f((u16)u); a1[0] += bf2f((u16)(u >> 16));
        } else {
            a0[0] += bf2f(h[(size_t)s * K + lane]);
        }
    }
    const float invd = 1.0f / fmaxf((float)dg, 1.0f);
    const float s0 = ((a0[0] + a0[1]) + (a0[2] + a0[3])) * invd;
    if constexpr (CL == 2) {
        const float s1 = ((a1[0] + a1[1]) + (a1[2] + a1[3])) * invd;
        u32 o = (u32)f2bf(s0) | ((u32)f2bf(s1) << 16);
        *reinterpret_cast<u32*>(&agg[(size_t)node * K + lane * 2]) = o;
    } else {
        agg[(size_t)node * K + lane] = f2bf(s0);
    }
}

// ---------------------------------------------------------------------------
// fused MFMA layer: pre = [agg | hin] @ [Wl ; Wc] + bc ; t = LN(pre)
//   FINAL=false: hout = (RELU ? relu(t) : t) as bf16 [N,128]
//   FINAL=true : sout[node] = t . ow  (fp32 scalar)
template <int K, bool RELU, bool FINAL>
__launch_bounds__(256)
__global__ void layer_mfma_kernel(const u16* __restrict__ aggbf,   // [N,K] (invd applied)
                                  const u16* __restrict__ hbf,     // [N,K]
                                  const u16* __restrict__ Wpack,   // fragment-ordered
                                  const float* __restrict__ bc,    // [128]
                                  const float* __restrict__ ln_g,  // [128]
                                  const float* __restrict__ ln_b,  // [128]
                                  const float* __restrict__ ow,    // [128] (FINAL)
                                  u16* __restrict__ hout,          // [N,128] (non-FINAL)
                                  float* __restrict__ sout) {      // [N]     (FINAL)
    constexpr int K2   = 2 * K;
    constexpr int NKS  = K2 / 32;     // MFMA k-steps
    constexpr int ROWB = K2 * 2;      // bytes per LDS row
    constexpr int CPR  = ROWB / 16;   // 16B chunks per row
    __shared__ __align__(16) char sA[64 * ROWB];

    const int tid  = threadIdx.x;
    const int lane = tid & 63;
    const int wid  = tid >> 6;
    const int base = blockIdx.x * 64;

    // ---- stage A tile (cols 0..K-1 = agg, K..2K-1 = hin), coalesced 16B ----
    for (int c = tid; c < 64 * CPR; c += 256) {
        int row = c / CPR, c16 = c % CPR;
        int rg = base + row; if (rg >= N_NODES) rg = N_NODES - 1;
        const u16* srcp = (c16 < CPR / 2) ? &aggbf[(size_t)rg * K + c16 * 8]
                                          : &hbf[(size_t)rg * K + (c16 - CPR / 2) * 8];
        float4 v = *reinterpret_cast<const float4*>(srcp);
        *reinterpret_cast<float4*>(&sA[row * ROWB + ((c16 * 16) ^ ((row & 7) << 4))]) = v;
    }
    __syncthreads();

    // ---- MFMA accumulate: 8 col-tiles of 16, rows = wave's 16 ----
    f32x4 acc[8];
    #pragma unroll
    for (int t = 0; t < 8; ++t) acc[t] = (f32x4){0.f, 0.f, 0.f, 0.f};

    const int arow = lane & 15;
    const int kg   = lane >> 4;
    const int lrow = wid * 16 + arow;               // LDS row
    #pragma unroll
    for (int ks = 0; ks < NKS; ++ks) {
        short8 af = *reinterpret_cast<const short8*>(
            &sA[lrow * ROWB + (((ks * 64 + kg * 16)) ^ ((lrow & 7) << 4))]);
        #pragma unroll
        for (int t = 0; t < 8; ++t) {
            short8 bf = *reinterpret_cast<const short8*>(&Wpack[(size_t)((ks * 8 + t) * 64 + lane) * 8]);
            acc[t] = __builtin_amdgcn_mfma_f32_16x16x32_bf16(af, bf, acc[t], 0, 0, 0);
        }
    }

    // ---- epilogue: +bias, LayerNorm per row (16-lane reduce), output ----
    // C layout: col = (lane&15) + 16*t ; row = wid*16 + (lane>>4)*4 + reg
    const int col0 = lane & 15;
    const int g    = lane >> 4;

    float lg[8], lb[8], wv[8];
    #pragma unroll
    for (int t = 0; t < 8; ++t) {
        const int col = col0 + 16 * t;
        const float cb = bc[col];
        lg[t] = ln_g[col]; lb[t] = ln_b[col];
        if (FINAL) wv[t] = ow[col];
        #pragma unroll
        for (int r = 0; r < 4; ++r) acc[t][r] += cb;
    }

    #pragma unroll
    for (int r = 0; r < 4; ++r) {
        float s = 0.f, q = 0.f;
        #pragma unroll
        for (int t = 0; t < 8; ++t) { s += acc[t][r]; q += acc[t][r] * acc[t][r]; }
        #pragma unroll
        for (int off = 8; off > 0; off >>= 1) {
            s += __shfl_xor(s, off, 64);
            q += __shfl_xor(q, off, 64);
        }
        const float mean = s * (1.0f / H_DIM);
        const float var  = q * (1.0f / H_DIM) - mean * mean;
        const float rstd = rsqrtf(var + LN_EPS);
        const int row = base + wid * 16 + g * 4 + r;

        if (FINAL) {
            float dot = 0.f;
            #pragma unroll
            for (int t = 0; t < 8; ++t) {
                float o = (acc[t][r] - mean) * rstd * lg[t] + lb[t];
                dot += o * wv[t];
            }
            #pragma unroll
            for (int off = 8; off > 0; off >>= 1) dot += __shfl_xor(dot, off, 64);
            if (col0 == 0 && row < N_NODES) sout[row] = dot;
        } else {
            if (row < N_NODES) {
                #pragma unroll
                for (int t = 0; t < 8; ++t) {
                    float o = (acc[t][r] - mean) * rstd * lg[t] + lb[t];
                    if (RELU) o = fmaxf(o, 0.f);
                    hout[(size_t)row * H_DIM + col0 + 16 * t] = f2bf(o);
                }
            }
        }
    }
}

// ---------------------------------------------------------------------------
__device__ __forceinline__ float waveReduceSum(float v) {
    #pragma unroll
    for (int off = 32; off > 0; off >>= 1) v += __shfl_xor(v, off, 64);
    return v;
}

// per-graph mean over contiguous node range (batch sorted), plus out_b
__global__ void graph_mean_kernel(const float* __restrict__ s, const int* __restrict__ start,
                                  const float* __restrict__ ob, float* __restrict__ out) {
    const int g = blockIdx.x;
    const int lane = threadIdx.x;
    const int a = start[g], b = start[g + 1];
    float sum = 0.f;
    for (int i = a + lane; i < b; i += 64) sum += s[i];
    sum = waveReduceSum(sum);
    if (lane == 0) out[g] = sum / fmaxf((float)(b - a), 1.0f) + ob[0];
}

// ---------------------------------------------------------------------------
static inline size_t align256(size_t x) { return (x + 255) & ~(size_t)255; }

extern "C" void kernel_launch(void* const* d_in, const int* in_sizes, int n_in,
                              void* d_out, int out_size, void* d_ws, size_t ws_size,
                              hipStream_t stream) {
    const float* x        = (const float*)d_in[0];
    const int*   eidx     = (const int*)d_in[1];
    const int*   batch    = (const int*)d_in[2];
    const float* lin_l0_w = (const float*)d_in[3];
    const float* lin_l0_b = (const float*)d_in[4];
    const float* lin_r0_w = (const float*)d_in[5];
    const float* res0_w   = (const float*)d_in[6];
    const float* res0_b   = (const float*)d_in[7];
    const float* ln0_g    = (const float*)d_in[8];
    const float* ln0_b    = (const float*)d_in[9];
    const float* lin_l1_w = (const float*)d_in[10];
    const float* lin_l1_b = (const float*)d_in[11];
    const float* lin_r1_w = (const float*)d_in[12];
    const float* res1_w   = (const float*)d_in[13];
    const float* res1_b   = (const float*)d_in[14];
    const float* ln1_g    = (const float*)d_in[15];
    const float* ln1_b    = (const float*)d_in[16];
    const float* out_w    = (const float*)d_in[17];
    const float* out_b    = (const float*)d_in[18];
    float* out = (float*)d_out;

    const int* src = eidx;
    const int* dst = eidx + N_EDGES;

    // workspace layout
    char* p = (char*)d_ws;
    int*   binCnt = (int*)p;  p += align256(256 * 4);
    int2*  binned = (int2*)p; p += align256((size_t)NBINS * BINCAP * 8);
    int*   degv   = (int*)p;  p += align256((size_t)N_NODES * 4);
    int*   bucket = (int*)p;  p += align256((size_t)N_NODES * CAP * 4);
    int*   gstart = (int*)p;  p += align256((size_t)(N_GRAPHS + 1) * 4);
    u16*   xbf    = (u16*)p;  p += align256((size_t)N_NODES * F_IN * 2);
    u16*   h0bf   = (u16*)p;  p += align256((size_t)N_NODES * H_DIM * 2);
    u16*   aggbf  = (u16*)p;  p += align256((size_t)N_NODES * H_DIM * 2);
    float* snode  = (float*)p; p += align256((size_t)N_NODES * 4);
    u16*   W0p    = (u16*)p;  p += align256((size_t)(2 * F_IN) * H_DIM * 2);
    u16*   W1p    = (u16*)p;  p += align256((size_t)(2 * H_DIM) * H_DIM * 2);
    float* bcc    = (float*)p; p += align256(256 * 4);

    hipMemsetAsync(binCnt, 0, 256 * 4, stream);

    // prep: convert x, combine biases, pack weights, graph bounds
    cvt_kernel<<<(N_NODES * F_IN / 4 + 255) / 256, 256, 0, stream>>>(x, xbf, N_NODES * F_IN / 4);
    bias_kernel<<<1, 128, 0, stream>>>(lin_l0_b, res0_b, lin_l1_b, res1_b, bcc);
    packw_kernel<<<(2048 + 255) / 256, 256, 0, stream>>>(lin_l0_w, lin_r0_w, res0_w, W0p, F_IN);
    packw_kernel<<<(4096 + 255) / 256, 256, 0, stream>>>(lin_l1_w, lin_r1_w, res1_w, W1p, H_DIM);
    bounds_kernel<<<(N_NODES + 255) / 256, 256, 0, stream>>>(batch, gstart);

    // two-phase edge bucketing (replaces global-atomic fill)
    partition_kernel<<<(N_EDGES + CHUNK - 1) / CHUNK, 256, 0, stream>>>(src, dst, binCnt, binned);
    fillbin_kernel<<<NBINS, 256, 0, stream>>>(binned, binCnt, bucket, degv);

    const int nTiles = (N_NODES + 63) / 64;

    // layer 0
    gather_kernel<F_IN><<<(N_NODES * 64 + 255) / 256, 256, 0, stream>>>(xbf, bucket, degv, aggbf);
    layer_mfma_kernel<F_IN, true, false><<<nTiles, 256, 0, stream>>>(
        aggbf, xbf, W0p, bcc, ln0_g, ln0_b, nullptr, h0bf, nullptr);

    // layer 1 (fused with out_w dot -> per-node scalar)
    gather_kernel<H_DIM><<<(N_NODES * 64 + 255) / 256, 256, 0, stream>>>(h0bf, bucket, degv, aggbf);
    layer_mfma_kernel<H_DIM, false, true><<<nTiles, 256, 0, stream>>>(
        aggbf, h0bf, W1p, bcc + 128, ln1_g, ln1_b, out_w, nullptr, snode);

    // per-graph mean + bias
    graph_mean_kernel<<<N_GRAPHS, 64, 0, stream>>>(snode, gstart, out_b, out);
}

// Round 6
// 142.515 us; speedup vs baseline: 16.6836x; 1.0252x over previous
//
#include <hip/hip_runtime.h>

#define N_NODES 50000
#define N_EDGES 800000
#define F_IN    64
#define H_DIM   128
#define N_GRAPHS 512
#define LN_EPS  1e-5f
#define CAP     64          // max in-degree bucket capacity (Poisson(16): P(deg>=64) ~ 1e-20)
#define NBINS   196         // ceil(50000/256) -- bin = dst >> 8
#define BINCAP  5120        // edges per bin region (E[bin]=4096, 16 sigma headroom)
#define CHUNK   4096        // edges per partition block

typedef short  short8 __attribute__((ext_vector_type(8)));
typedef float  f32x4  __attribute__((ext_vector_type(4)));
typedef unsigned short u16;
typedef unsigned int   u32;

__device__ __forceinline__ float bf2f(u16 u) {
    u32 b = ((u32)u) << 16;
    return __builtin_bit_cast(float, b);
}
__device__ __forceinline__ u16 f2bf(float f) {   // round-to-nearest-even
    u32 b = __builtin_bit_cast(u32, f);
    return (u16)((b + 0x7FFFu + ((b >> 16) & 1u)) >> 16);
}

// ---------------------------------------------------------------------------
// fp32 -> bf16 bulk convert (4 elems/thread)
__global__ void cvt_kernel(const float* __restrict__ in, u16* __restrict__ out, int n4) {
    int i = blockIdx.x * blockDim.x + threadIdx.x;
    if (i >= n4) return;
    float4 v = reinterpret_cast<const float4*>(in)[i];
    ushort4 o;
    o.x = f2bf(v.x); o.y = f2bf(v.y); o.z = f2bf(v.z); o.w = f2bf(v.w);
    reinterpret_cast<ushort4*>(out)[i] = o;
}

// ---------------------------------------------------------------------------
// combine both layer biases + zero binCnt (replaces hipMemsetAsync: the
// rocclr fillBufferAligned node cost ~41us/replay in-graph)
__global__ void bias_kernel(const float* __restrict__ a0, const float* __restrict__ b0,
                            const float* __restrict__ a1, const float* __restrict__ b1,
                            float* __restrict__ o, int* __restrict__ binCnt) {
    int i = threadIdx.x;   // 128
    o[i]       = a0[i] + b0[i];
    o[128 + i] = a1[i] + b1[i];
    binCnt[i] = 0;
    binCnt[128 + i] = 0;
}

// ---------------------------------------------------------------------------
// pack weights into MFMA B-fragment order, bf16.
// Logical W' [2K x 128]: rows 0..K-1 = Wl, rows K..2K-1 = Wr + Rw.
__global__ void packw_kernel(const float* __restrict__ Wl, const float* __restrict__ Wr,
                             const float* __restrict__ Rw, u16* __restrict__ out, int K) {
    int tid = blockIdx.x * blockDim.x + threadIdx.x;
    int total = ((2 * K) / 32) * 8 * 64;
    if (tid >= total) return;
    int lane = tid & 63;
    int tile = (tid >> 6) & 7;
    int kstep = tid >> 9;
    int col = tile * 16 + (lane & 15);
    short8 o;
    #pragma unroll
    for (int e = 0; e < 8; ++e) {
        int k = kstep * 32 + (lane >> 4) * 8 + e;
        float v = (k < K) ? Wl[(size_t)k * H_DIM + col]
                          : (Wr[(size_t)(k - K) * H_DIM + col] + Rw[(size_t)(k - K) * H_DIM + col]);
        o[e] = (short)f2bf(v);
    }
    *reinterpret_cast<short8*>(&out[(size_t)tid * 8]) = o;
}

// ---------------------------------------------------------------------------
// Phase 1: partition edges into NBINS coarse bins (bin = dst>>8), coalesced runs.
__launch_bounds__(256)
__global__ void partition_kernel(const int* __restrict__ src, const int* __restrict__ dst,
                                 int* __restrict__ binCnt, int2* __restrict__ binned) {
    __shared__ int2 lbuf[CHUNK];
    __shared__ int sHist[256];
    __shared__ int sScan[256];
    __shared__ int sCur[256];
    __shared__ int sGBase[256];
    const int tid = threadIdx.x;
    const int base = blockIdx.x * CHUNK;
    const int cnt = min(CHUNK, N_EDGES - base);

    // load up to 16 edges/thread into registers (coalesced)
    int2 ed[16];
    int nb[16];
    #pragma unroll
    for (int i = 0; i < 16; ++i) {
        int idx = base + i * 256 + tid;
        if (idx < N_EDGES) { ed[i].x = src[idx]; ed[i].y = dst[idx]; nb[i] = ed[i].y >> 8; }
        else nb[i] = -1;
    }
    sHist[tid] = 0;
    __syncthreads();
    #pragma unroll
    for (int i = 0; i < 16; ++i) if (nb[i] >= 0) atomicAdd(&sHist[nb[i]], 1);
    __syncthreads();

    // inclusive Hillis-Steele scan over 256
    sScan[tid] = sHist[tid];
    __syncthreads();
    for (int off = 1; off < 256; off <<= 1) {
        int v = sScan[tid];
        int add = (tid >= off) ? sScan[tid - off] : 0;
        __syncthreads();
        sScan[tid] = v + add;
        __syncthreads();
    }
    int excl = sScan[tid] - sHist[tid];
    __syncthreads();
    sScan[tid] = excl;           // exclusive scan, kept for copy-out
    sCur[tid]  = excl;           // atomic cursor for LDS reorder
    if (tid < NBINS && sHist[tid] > 0)
        sGBase[tid] = atomicAdd(&binCnt[tid], sHist[tid]);   // reserve global range
    __syncthreads();

    // reorder chunk into LDS, grouped by bin
    #pragma unroll
    for (int i = 0; i < 16; ++i) {
        if (nb[i] >= 0) {
            int p = atomicAdd(&sCur[nb[i]], 1);
            lbuf[p] = ed[i];
        }
    }
    __syncthreads();

    // copy out: consecutive t within a bin-run -> consecutive global slots
    for (int t = tid; t < cnt; t += 256) {
        int2 e = lbuf[t];
        int b = e.y >> 8;
        int slot = sGBase[b] + (t - sScan[b]);
        if (slot < BINCAP) binned[(size_t)b * BINCAP + slot] = e;
    }
}

// ---------------------------------------------------------------------------
// Phase 2: per-bin bucket fill; per-node cursors in LDS, bucket region L2-hot.
__launch_bounds__(256)
__global__ void fillbin_kernel(const int2* __restrict__ binned, const int* __restrict__ binCnt,
                               int* __restrict__ bucket, int* __restrict__ degv) {
    __shared__ int lcur[256];
    const int b = blockIdx.x;
    const int tid = threadIdx.x;
    const int nodeBase = b << 8;
    lcur[tid] = 0;
    __syncthreads();
    int cnt = binCnt[b];
    if (cnt > BINCAP) cnt = BINCAP;
    const int2* be = &binned[(size_t)b * BINCAP];
    for (int t = tid; t < cnt; t += 256) {
        int2 e = be[t];
        int pos = atomicAdd(&lcur[e.y & 255], 1);
        if (pos < CAP) bucket[(size_t)e.y * CAP + pos] = e.x;
    }
    __syncthreads();
    int node = nodeBase + tid;
    if (node < N_NODES) degv[node] = lcur[tid];
}

// ---------------------------------------------------------------------------
// graph boundaries from sorted batch
__global__ void bounds_kernel(const int* __restrict__ batch, int* __restrict__ start) {
    int i = blockIdx.x * blockDim.x + threadIdx.x;
    if (i >= N_NODES) return;
    int b = batch[i];
    int prev = (i == 0) ? -1 : batch[i - 1];
    for (int g = prev + 1; g <= b; ++g) start[g] = i;
    if (i == N_NODES - 1)
        for (int g = b + 1; g <= N_GRAPHS; ++g) start[g] = N_NODES;
}

// ---------------------------------------------------------------------------
// gather-aggregate (bf16 in, bf16 out, fp32 accumulate, mean applied here)
template <int K>
__launch_bounds__(256)
__global__ void gather_kernel(const u16* __restrict__ h, const int* __restrict__ bucket,
                              const int* __restrict__ degv, u16* __restrict__ agg) {
    constexpr int CL = K / 64;       // cols per lane: 1 (K=64) or 2 (K=128)
    const int node = (blockIdx.x * blockDim.x + threadIdx.x) >> 6;
    const int lane = threadIdx.x & 63;
    if (node >= N_NODES) return;
    int dg = degv[node];
    int dgc = dg > CAP ? CAP : dg;
    const int* bk = &bucket[(size_t)node * CAP];

    float a0[4] = {0.f, 0.f, 0.f, 0.f};
    float a1[4] = {0.f, 0.f, 0.f, 0.f};

    int e = 0;
    for (; e + 4 <= dgc; e += 4) {
        int s0 = bk[e], s1 = bk[e + 1], s2 = bk[e + 2], s3 = bk[e + 3];
        if constexpr (CL == 2) {
            u32 u0 = *reinterpret_cast<const u32*>(&h[(size_t)s0 * K + lane * 2]);
            u32 u1 = *reinterpret_cast<const u32*>(&h[(size_t)s1 * K + lane * 2]);
            u32 u2 = *reinterpret_cast<const u32*>(&h[(size_t)s2 * K + lane * 2]);
            u32 u3 = *reinterpret_cast<const u32*>(&h[(size_t)s3 * K + lane * 2]);
            a0[0] += bf2f((u16)u0); a1[0] += bf2f((u16)(u0 >> 16));
            a0[1] += bf2f((u16)u1); a1[1] += bf2f((u16)(u1 >> 16));
            a0[2] += bf2f((u16)u2); a1[2] += bf2f((u16)(u2 >> 16));
            a0[3] += bf2f((u16)u3); a1[3] += bf2f((u16)(u3 >> 16));
        } else {
            a0[0] += bf2f(h[(size_t)s0 * K + lane]);
            a0[1] += bf2f(h[(size_t)s1 * K + lane]);
            a0[2] += bf2f(h[(size_t)s2 * K + lane]);
            a0[3] += bf2f(h[(size_t)s3 * K + lane]);
        }
    }
    for (; e < dgc; ++e) {
        int s = bk[e];
        if constexpr (CL == 2) {
            u32 u = *reinterpret_cast<const u32*>(&h[(size_t)s * K + lane * 2]);
            a0[0] += bf2f((u16)u); a1[0] += bf2f((u16)(u >> 16));
        } else {
            a0[0] += bf2f(h[(size_t)s * K + lane]);
        }
    }
    const float invd = 1.0f / fmaxf((float)dg, 1.0f);
    const float s0 = ((a0[0] + a0[1]) + (a0[2] + a0[3])) * invd;
    if constexpr (CL == 2) {
        const float s1 = ((a1[0] + a1[1]) + (a1[2] + a1[3])) * invd;
        u32 o = (u32)f2bf(s0) | ((u32)f2bf(s1) << 16);
        *reinterpret_cast<u32*>(&agg[(size_t)node * K + lane * 2]) = o;
    } else {
        agg[(size_t)node * K + lane] = f2bf(s0);
    }
}

// ---------------------------------------------------------------------------
// fused MFMA layer: pre = [agg | hin] @ [Wl ; Wc] + bc ; t = LN(pre)
//   FINAL=false: hout = (RELU ? relu(t) : t) as bf16 [N,128]
//   FINAL=true : sout[node] = t . ow  (fp32 scalar)
template <int K, bool RELU, bool FINAL>
__launch_bounds__(256)
__global__ void layer_mfma_kernel(const u16* __restrict__ aggbf,   // [N,K] (invd applied)
                                  const u16* __restrict__ hbf,     // [N,K]
                                  const u16* __restrict__ Wpack,   // fragment-ordered
                                  const float* __restrict__ bc,    // [128]
                                  const float* __restrict__ ln_g,  // [128]
                                  const float* __restrict__ ln_b,  // [128]
                                  const float* __restrict__ ow,    // [128] (FINAL)
                                  u16* __restrict__ hout,          // [N,128] (non-FINAL)
                                  float* __restrict__ sout) {      // [N]     (FINAL)
    constexpr int K2   = 2 * K;
    constexpr int NKS  = K2 / 32;     // MFMA k-steps
    constexpr int ROWB = K2 * 2;      // bytes per LDS row
    constexpr int CPR  = ROWB / 16;   // 16B chunks per row
    __shared__ __align__(16) char sA[64 * ROWB];

    const int tid  = threadIdx.x;
    const int lane = tid & 63;
    const int wid  = tid >> 6;
    const int base = blockIdx.x * 64;

    // ---- stage A tile (cols 0..K-1 = agg, K..2K-1 = hin), coalesced 16B ----
    for (int c = tid; c < 64 * CPR; c += 256) {
        int row = c / CPR, c16 = c % CPR;
        int rg = base + row; if (rg >= N_NODES) rg = N_NODES - 1;
        const u16* srcp = (c16 < CPR / 2) ? &aggbf[(size_t)rg * K + c16 * 8]
                                          : &hbf[(size_t)rg * K + (c16 - CPR / 2) * 8];
        float4 v = *reinterpret_cast<const float4*>(srcp);
        *reinterpret_cast<float4*>(&sA[row * ROWB + ((c16 * 16) ^ ((row & 7) << 4))]) = v;
    }
    __syncthreads();

    // ---- MFMA accumulate: 8 col-tiles of 16, rows = wave's 16 ----
    f32x4 acc[8];
    #pragma unroll
    for (int t = 0; t < 8; ++t) acc[t] = (f32x4){0.f, 0.f, 0.f, 0.f};

    const int arow = lane & 15;
    const int kg   = lane >> 4;
    const int lrow = wid * 16 + arow;               // LDS row
    #pragma unroll
    for (int ks = 0; ks < NKS; ++ks) {
        short8 af = *reinterpret_cast<const short8*>(
            &sA[lrow * ROWB + (((ks * 64 + kg * 16)) ^ ((lrow & 7) << 4))]);
        #pragma unroll
        for (int t = 0; t < 8; ++t) {
            short8 bf = *reinterpret_cast<const short8*>(&Wpack[(size_t)((ks * 8 + t) * 64 + lane) * 8]);
            acc[t] = __builtin_amdgcn_mfma_f32_16x16x32_bf16(af, bf, acc[t], 0, 0, 0);
        }
    }

    // ---- epilogue: +bias, LayerNorm per row (16-lane reduce), output ----
    // C layout: col = (lane&15) + 16*t ; row = wid*16 + (lane>>4)*4 + reg
    const int col0 = lane & 15;
    const int g    = lane >> 4;

    float lg[8], lb[8], wv[8];
    #pragma unroll
    for (int t = 0; t < 8; ++t) {
        const int col = col0 + 16 * t;
        const float cb = bc[col];
        lg[t] = ln_g[col]; lb[t] = ln_b[col];
        if (FINAL) wv[t] = ow[col];
        #pragma unroll
        for (int r = 0; r < 4; ++r) acc[t][r] += cb;
    }

    #pragma unroll
    for (int r = 0; r < 4; ++r) {
        float s = 0.f, q = 0.f;
        #pragma unroll
        for (int t = 0; t < 8; ++t) { s += acc[t][r]; q += acc[t][r] * acc[t][r]; }
        #pragma unroll
        for (int off = 8; off > 0; off >>= 1) {
            s += __shfl_xor(s, off, 64);
            q += __shfl_xor(q, off, 64);
        }
        const float mean = s * (1.0f / H_DIM);
        const float var  = q * (1.0f / H_DIM) - mean * mean;
        const float rstd = rsqrtf(var + LN_EPS);
        const int row = base + wid * 16 + g * 4 + r;

        if (FINAL) {
            float dot = 0.f;
            #pragma unroll
            for (int t = 0; t < 8; ++t) {
                float o = (acc[t][r] - mean) * rstd * lg[t] + lb[t];
                dot += o * wv[t];
            }
            #pragma unroll
            for (int off = 8; off > 0; off >>= 1) dot += __shfl_xor(dot, off, 64);
            if (col0 == 0 && row < N_NODES) sout[row] = dot;
        } else {
            if (row < N_NODES) {
                #pragma unroll
                for (int t = 0; t < 8; ++t) {
                    float o = (acc[t][r] - mean) * rstd * lg[t] + lb[t];
                    if (RELU) o = fmaxf(o, 0.f);
                    hout[(size_t)row * H_DIM + col0 + 16 * t] = f2bf(o);
                }
            }
        }
    }
}

// ---------------------------------------------------------------------------
__device__ __forceinline__ float waveReduceSum(float v) {
    #pragma unroll
    for (int off = 32; off > 0; off >>= 1) v += __shfl_xor(v, off, 64);
    return v;
}

// per-graph mean over contiguous node range (batch sorted), plus out_b
__global__ void graph_mean_kernel(const float* __restrict__ s, const int* __restrict__ start,
                                  const float* __restrict__ ob, float* __restrict__ out) {
    const int g = blockIdx.x;
    const int lane = threadIdx.x;
    const int a = start[g], b = start[g + 1];
    float sum = 0.f;
    for (int i = a + lane; i < b; i += 64) sum += s[i];
    sum = waveReduceSum(sum);
    if (lane == 0) out[g] = sum / fmaxf((float)(b - a), 1.0f) + ob[0];
}

// ---------------------------------------------------------------------------
static inline size_t align256(size_t x) { return (x + 255) & ~(size_t)255; }

extern "C" void kernel_launch(void* const* d_in, const int* in_sizes, int n_in,
                              void* d_out, int out_size, void* d_ws, size_t ws_size,
                              hipStream_t stream) {
    const float* x        = (const float*)d_in[0];
    const int*   eidx     = (const int*)d_in[1];
    const int*   batch    = (const int*)d_in[2];
    const float* lin_l0_w = (const float*)d_in[3];
    const float* lin_l0_b = (const float*)d_in[4];
    const float* lin_r0_w = (const float*)d_in[5];
    const float* res0_w   = (const float*)d_in[6];
    const float* res0_b   = (const float*)d_in[7];
    const float* ln0_g    = (const float*)d_in[8];
    const float* ln0_b    = (const float*)d_in[9];
    const float* lin_l1_w = (const float*)d_in[10];
    const float* lin_l1_b = (const float*)d_in[11];
    const float* lin_r1_w = (const float*)d_in[12];
    const float* res1_w   = (const float*)d_in[13];
    const float* res1_b   = (const float*)d_in[14];
    const float* ln1_g    = (const float*)d_in[15];
    const float* ln1_b    = (const float*)d_in[16];
    const float* out_w    = (const float*)d_in[17];
    const float* out_b    = (const float*)d_in[18];
    float* out = (float*)d_out;

    const int* src = eidx;
    const int* dst = eidx + N_EDGES;

    // workspace layout
    char* p = (char*)d_ws;
    int*   binCnt = (int*)p;  p += align256(256 * 4);
    int2*  binned = (int2*)p; p += align256((size_t)NBINS * BINCAP * 8);
    int*   degv   = (int*)p;  p += align256((size_t)N_NODES * 4);
    int*   bucket = (int*)p;  p += align256((size_t)N_NODES * CAP * 4);
    int*   gstart = (int*)p;  p += align256((size_t)(N_GRAPHS + 1) * 4);
    u16*   xbf    = (u16*)p;  p += align256((size_t)N_NODES * F_IN * 2);
    u16*   h0bf   = (u16*)p;  p += align256((size_t)N_NODES * H_DIM * 2);
    u16*   aggbf  = (u16*)p;  p += align256((size_t)N_NODES * H_DIM * 2);
    float* snode  = (float*)p; p += align256((size_t)N_NODES * 4);
    u16*   W0p    = (u16*)p;  p += align256((size_t)(2 * F_IN) * H_DIM * 2);
    u16*   W1p    = (u16*)p;  p += align256((size_t)(2 * H_DIM) * H_DIM * 2);
    float* bcc    = (float*)p; p += align256(256 * 4);

    // prep: convert x, combine biases (+zero binCnt), pack weights, graph bounds
    cvt_kernel<<<(N_NODES * F_IN / 4 + 255) / 256, 256, 0, stream>>>(x, xbf, N_NODES * F_IN / 4);
    bias_kernel<<<1, 128, 0, stream>>>(lin_l0_b, res0_b, lin_l1_b, res1_b, bcc, binCnt);
    packw_kernel<<<(2048 + 255) / 256, 256, 0, stream>>>(lin_l0_w, lin_r0_w, res0_w, W0p, F_IN);
    packw_kernel<<<(4096 + 255) / 256, 256, 0, stream>>>(lin_l1_w, lin_r1_w, res1_w, W1p, H_DIM);
    bounds_kernel<<<(N_NODES + 255) / 256, 256, 0, stream>>>(batch, gstart);

    // two-phase edge bucketing (replaces global-atomic fill)
    partition_kernel<<<(N_EDGES + CHUNK - 1) / CHUNK, 256, 0, stream>>>(src, dst, binCnt, binned);
    fillbin_kernel<<<NBINS, 256, 0, stream>>>(binned, binCnt, bucket, degv);

    const int nTiles = (N_NODES + 63) / 64;

    // layer 0
    gather_kernel<F_IN><<<(N_NODES * 64 + 255) / 256, 256, 0, stream>>>(xbf, bucket, degv, aggbf);
    layer_mfma_kernel<F_IN, true, false><<<nTiles, 256, 0, stream>>>(
        aggbf, xbf, W0p, bcc, ln0_g, ln0_b, nullptr, h0bf, nullptr);

    // layer 1 (fused with out_w dot -> per-node scalar)
    gather_kernel<H_DIM><<<(N_NODES * 64 + 255) / 256, 256, 0, stream>>>(h0bf, bucket, degv, aggbf);
    layer_mfma_kernel<H_DIM, false, true><<<nTiles, 256, 0, stream>>>(
        aggbf, h0bf, W1p, bcc + 128, ln1_g, ln1_b, out_w, nullptr, snode);

    // per-graph mean + bias
    graph_mean_kernel<<<N_GRAPHS, 64, 0, stream>>>(snode, gstart, out_b, out);
}

// Round 7
// 139.532 us; speedup vs baseline: 17.0403x; 1.0214x over previous
//
#include <hip/hip_runtime.h>

#define N_NODES 50000
#define N_EDGES 800000
#define F_IN    64
#define H_DIM   128
#define N_GRAPHS 512
#define LN_EPS  1e-5f
#define CAP     64          // max in-degree bucket capacity (Poisson(16): P(deg>=64) ~ 1e-20)
#define NBINS   196         // ceil(50000/256) -- bin = dst >> 8
#define BINCAP  5120        // edges per bin region (E[bin]=4096, 16 sigma headroom)
#define CHUNK   4096        // edges per partition block

typedef short  short8 __attribute__((ext_vector_type(8)));
typedef float  f32x4  __attribute__((ext_vector_type(4)));
typedef unsigned short u16;
typedef unsigned int   u32;

__device__ __forceinline__ float bf2f(u16 u) {
    u32 b = ((u32)u) << 16;
    return __builtin_bit_cast(float, b);
}
__device__ __forceinline__ u16 f2bf(float f) {   // round-to-nearest-even
    u32 b = __builtin_bit_cast(u32, f);
    return (u16)((b + 0x7FFFu + ((b >> 16) & 1u)) >> 16);
}

// ---------------------------------------------------------------------------
// pack weights into MFMA B-fragment order, bf16 (device helper).
// Logical W' [2K x 128]: rows 0..K-1 = Wl, rows K..2K-1 = Wr + Rw.
__device__ __forceinline__ void packw_body(const float* __restrict__ Wl,
                                           const float* __restrict__ Wr,
                                           const float* __restrict__ Rw,
                                           u16* __restrict__ out, int K, int tid) {
    int lane = tid & 63;
    int tile = (tid >> 6) & 7;
    int kstep = tid >> 9;
    int col = tile * 16 + (lane & 15);
    short8 o;
    #pragma unroll
    for (int e = 0; e < 8; ++e) {
        int k = kstep * 32 + (lane >> 4) * 8 + e;
        float v = (k < K) ? Wl[(size_t)k * H_DIM + col]
                          : (Wr[(size_t)(k - K) * H_DIM + col] + Rw[(size_t)(k - K) * H_DIM + col]);
        o[e] = (short)f2bf(v);
    }
    *reinterpret_cast<short8*>(&out[(size_t)tid * 8]) = o;
}

// ---------------------------------------------------------------------------
// fused prep: cvt(x->bf16) | bias-combine+binCnt-zero | packw0 | packw1 | bounds
// single launch, dispatched by blockIdx range (all parts independent).
#define CVT_BLOCKS   3125     // 50000*64/4 / 256
#define PW0_BLOCKS   8        // 2048 threads
#define PW1_BLOCKS   16       // 4096 threads
#define BND_BLOCKS   196      // ceil(50000/256)
__launch_bounds__(256)
__global__ void prep_kernel(const float* __restrict__ x, u16* __restrict__ xbf,
                            const float* __restrict__ l0b, const float* __restrict__ r0b,
                            const float* __restrict__ l1b, const float* __restrict__ r1b,
                            float* __restrict__ bcc, int* __restrict__ binCnt,
                            const float* __restrict__ Wl0, const float* __restrict__ Wr0,
                            const float* __restrict__ Rw0, u16* __restrict__ W0p,
                            const float* __restrict__ Wl1, const float* __restrict__ Wr1,
                            const float* __restrict__ Rw1, u16* __restrict__ W1p,
                            const int* __restrict__ batch, int* __restrict__ gstart) {
    const int b = blockIdx.x;
    const int tid = threadIdx.x;
    if (b < CVT_BLOCKS) {
        int i = b * 256 + tid;                       // < 800000 exactly
        float4 v = reinterpret_cast<const float4*>(x)[i];
        ushort4 o;
        o.x = f2bf(v.x); o.y = f2bf(v.y); o.z = f2bf(v.z); o.w = f2bf(v.w);
        reinterpret_cast<ushort4*>(xbf)[i] = o;
    } else if (b == CVT_BLOCKS) {
        if (tid < 128) {
            bcc[tid]       = l0b[tid] + r0b[tid];
            bcc[128 + tid] = l1b[tid] + r1b[tid];
            binCnt[tid] = 0;
            binCnt[128 + tid] = 0;
        }
    } else if (b < CVT_BLOCKS + 1 + PW0_BLOCKS) {
        packw_body(Wl0, Wr0, Rw0, W0p, F_IN, (b - CVT_BLOCKS - 1) * 256 + tid);
    } else if (b < CVT_BLOCKS + 1 + PW0_BLOCKS + PW1_BLOCKS) {
        packw_body(Wl1, Wr1, Rw1, W1p, H_DIM, (b - CVT_BLOCKS - 1 - PW0_BLOCKS) * 256 + tid);
    } else {
        int i = (b - CVT_BLOCKS - 1 - PW0_BLOCKS - PW1_BLOCKS) * 256 + tid;
        if (i >= N_NODES) return;
        int bb = batch[i];
        int prev = (i == 0) ? -1 : batch[i - 1];
        for (int g = prev + 1; g <= bb; ++g) gstart[g] = i;
        if (i == N_NODES - 1)
            for (int g = bb + 1; g <= N_GRAPHS; ++g) gstart[g] = N_NODES;
    }
}

// ---------------------------------------------------------------------------
// Phase 1: partition edges into NBINS coarse bins (bin = dst>>8), coalesced runs.
__launch_bounds__(256)
__global__ void partition_kernel(const int* __restrict__ src, const int* __restrict__ dst,
                                 int* __restrict__ binCnt, int2* __restrict__ binned) {
    __shared__ int2 lbuf[CHUNK];
    __shared__ int sHist[256];
    __shared__ int sScan[256];
    __shared__ int sCur[256];
    __shared__ int sGBase[256];
    const int tid = threadIdx.x;
    const int base = blockIdx.x * CHUNK;
    const int cnt = min(CHUNK, N_EDGES - base);

    // load up to 16 edges/thread into registers (coalesced)
    int2 ed[16];
    int nb[16];
    #pragma unroll
    for (int i = 0; i < 16; ++i) {
        int idx = base + i * 256 + tid;
        if (idx < N_EDGES) { ed[i].x = src[idx]; ed[i].y = dst[idx]; nb[i] = ed[i].y >> 8; }
        else nb[i] = -1;
    }
    sHist[tid] = 0;
    __syncthreads();
    #pragma unroll
    for (int i = 0; i < 16; ++i) if (nb[i] >= 0) atomicAdd(&sHist[nb[i]], 1);
    __syncthreads();

    // inclusive Hillis-Steele scan over 256
    sScan[tid] = sHist[tid];
    __syncthreads();
    for (int off = 1; off < 256; off <<= 1) {
        int v = sScan[tid];
        int add = (tid >= off) ? sScan[tid - off] : 0;
        __syncthreads();
        sScan[tid] = v + add;
        __syncthreads();
    }
    int excl = sScan[tid] - sHist[tid];
    __syncthreads();
    sScan[tid] = excl;           // exclusive scan, kept for copy-out
    sCur[tid]  = excl;           // atomic cursor for LDS reorder
    if (tid < NBINS && sHist[tid] > 0)
        sGBase[tid] = atomicAdd(&binCnt[tid], sHist[tid]);   // reserve global range
    __syncthreads();

    // reorder chunk into LDS, grouped by bin
    #pragma unroll
    for (int i = 0; i < 16; ++i) {
        if (nb[i] >= 0) {
            int p = atomicAdd(&sCur[nb[i]], 1);
            lbuf[p] = ed[i];
        }
    }
    __syncthreads();

    // copy out: consecutive t within a bin-run -> consecutive global slots
    for (int t = tid; t < cnt; t += 256) {
        int2 e = lbuf[t];
        int b = e.y >> 8;
        int slot = sGBase[b] + (t - sScan[b]);
        if (slot < BINCAP) binned[(size_t)b * BINCAP + slot] = e;
    }
}

// ---------------------------------------------------------------------------
// Phase 2: per-bin bucket fill; per-node cursors in LDS, bucket region L2-hot.
__launch_bounds__(256)
__global__ void fillbin_kernel(const int2* __restrict__ binned, const int* __restrict__ binCnt,
                               int* __restrict__ bucket, int* __restrict__ degv) {
    __shared__ int lcur[256];
    const int b = blockIdx.x;
    const int tid = threadIdx.x;
    const int nodeBase = b << 8;
    lcur[tid] = 0;
    __syncthreads();
    int cnt = binCnt[b];
    if (cnt > BINCAP) cnt = BINCAP;
    const int2* be = &binned[(size_t)b * BINCAP];
    for (int t = tid; t < cnt; t += 256) {
        int2 e = be[t];
        int pos = atomicAdd(&lcur[e.y & 255], 1);
        if (pos < CAP) bucket[(size_t)e.y * CAP + pos] = e.x;
    }
    __syncthreads();
    int node = nodeBase + tid;
    if (node < N_NODES) degv[node] = lcur[tid];
}

// ---------------------------------------------------------------------------
// gather-aggregate (bf16 in, bf16 out, fp32 accumulate, mean applied here)
// 8 independent accumulator groups -> 8 row-loads in flight per wave.
template <int K>
__launch_bounds__(256)
__global__ void gather_kernel(const u16* __restrict__ h, const int* __restrict__ bucket,
                              const int* __restrict__ degv, u16* __restrict__ agg) {
    const int node = (blockIdx.x * blockDim.x + threadIdx.x) >> 6;
    const int lane = threadIdx.x & 63;
    if (node >= N_NODES) return;
    int dg = degv[node];
    int dgc = dg > CAP ? CAP : dg;
    const int* bk = &bucket[(size_t)node * CAP];

    float a0[8], a1[8];
    #pragma unroll
    for (int u = 0; u < 8; ++u) { a0[u] = 0.f; a1[u] = 0.f; }

    int e = 0;
    for (; e + 8 <= dgc; e += 8) {
        int4 q0 = *reinterpret_cast<const int4*>(&bk[e]);
        int4 q1 = *reinterpret_cast<const int4*>(&bk[e + 4]);
        int s[8] = {q0.x, q0.y, q0.z, q0.w, q1.x, q1.y, q1.z, q1.w};
        if constexpr (K == 128) {
            u32 w[8];
            #pragma unroll
            for (int u = 0; u < 8; ++u)
                w[u] = *reinterpret_cast<const u32*>(&h[(size_t)s[u] * K + lane * 2]);
            #pragma unroll
            for (int u = 0; u < 8; ++u) {
                a0[u] += bf2f((u16)w[u]);
                a1[u] += bf2f((u16)(w[u] >> 16));
            }
        } else {
            u16 w[8];
            #pragma unroll
            for (int u = 0; u < 8; ++u) w[u] = h[(size_t)s[u] * K + lane];
            #pragma unroll
            for (int u = 0; u < 8; ++u) a0[u] += bf2f(w[u]);
        }
    }
    for (; e < dgc; ++e) {
        int s = bk[e];
        if constexpr (K == 128) {
            u32 w = *reinterpret_cast<const u32*>(&h[(size_t)s * K + lane * 2]);
            a0[e & 7] += bf2f((u16)w);
            a1[e & 7] += bf2f((u16)(w >> 16));
        } else {
            a0[e & 7] += bf2f(h[(size_t)s * K + lane]);
        }
    }
    const float invd = 1.0f / fmaxf((float)dg, 1.0f);
    const float s0 = (((a0[0] + a0[1]) + (a0[2] + a0[3])) + ((a0[4] + a0[5]) + (a0[6] + a0[7]))) * invd;
    if constexpr (K == 128) {
        const float s1 = (((a1[0] + a1[1]) + (a1[2] + a1[3])) + ((a1[4] + a1[5]) + (a1[6] + a1[7]))) * invd;
        u32 o = (u32)f2bf(s0) | ((u32)f2bf(s1) << 16);
        *reinterpret_cast<u32*>(&agg[(size_t)node * K + lane * 2]) = o;
    } else {
        agg[(size_t)node * K + lane] = f2bf(s0);
    }
}

// ---------------------------------------------------------------------------
// fused MFMA layer: pre = [agg | hin] @ [Wl ; Wc] + bc ; t = LN(pre)
//   FINAL=false: hout = (RELU ? relu(t) : t) as bf16 [N,128]
//   FINAL=true : sout[node] = t . ow  (fp32 scalar)
template <int K, bool RELU, bool FINAL>
__launch_bounds__(256)
__global__ void layer_mfma_kernel(const u16* __restrict__ aggbf,   // [N,K] (invd applied)
                                  const u16* __restrict__ hbf,     // [N,K]
                                  const u16* __restrict__ Wpack,   // fragment-ordered
                                  const float* __restrict__ bc,    // [128]
                                  const float* __restrict__ ln_g,  // [128]
                                  const float* __restrict__ ln_b,  // [128]
                                  const float* __restrict__ ow,    // [128] (FINAL)
                                  u16* __restrict__ hout,          // [N,128] (non-FINAL)
                                  float* __restrict__ sout) {      // [N]     (FINAL)
    constexpr int K2   = 2 * K;
    constexpr int NKS  = K2 / 32;     // MFMA k-steps
    constexpr int ROWB = K2 * 2;      // bytes per LDS row
    constexpr int CPR  = ROWB / 16;   // 16B chunks per row
    __shared__ __align__(16) char sA[64 * ROWB];

    const int tid  = threadIdx.x;
    const int lane = tid & 63;
    const int wid  = tid >> 6;
    const int base = blockIdx.x * 64;

    // ---- stage A tile (cols 0..K-1 = agg, K..2K-1 = hin), coalesced 16B ----
    for (int c = tid; c < 64 * CPR; c += 256) {
        int row = c / CPR, c16 = c % CPR;
        int rg = base + row; if (rg >= N_NODES) rg = N_NODES - 1;
        const u16* srcp = (c16 < CPR / 2) ? &aggbf[(size_t)rg * K + c16 * 8]
                                          : &hbf[(size_t)rg * K + (c16 - CPR / 2) * 8];
        float4 v = *reinterpret_cast<const float4*>(srcp);
        *reinterpret_cast<float4*>(&sA[row * ROWB + ((c16 * 16) ^ ((row & 7) << 4))]) = v;
    }
    __syncthreads();

    // ---- MFMA accumulate: 8 col-tiles of 16, rows = wave's 16 ----
    f32x4 acc[8];
    #pragma unroll
    for (int t = 0; t < 8; ++t) acc[t] = (f32x4){0.f, 0.f, 0.f, 0.f};

    const int arow = lane & 15;
    const int kg   = lane >> 4;
    const int lrow = wid * 16 + arow;               // LDS row
    #pragma unroll
    for (int ks = 0; ks < NKS; ++ks) {
        short8 af = *reinterpret_cast<const short8*>(
            &sA[lrow * ROWB + (((ks * 64 + kg * 16)) ^ ((lrow & 7) << 4))]);
        #pragma unroll
        for (int t = 0; t < 8; ++t) {
            short8 bf = *reinterpret_cast<const short8*>(&Wpack[(size_t)((ks * 8 + t) * 64 + lane) * 8]);
            acc[t] = __builtin_amdgcn_mfma_f32_16x16x32_bf16(af, bf, acc[t], 0, 0, 0);
        }
    }

    // ---- epilogue: +bias, LayerNorm per row (16-lane reduce), output ----
    // C layout: col = (lane&15) + 16*t ; row = wid*16 + (lane>>4)*4 + reg
    const int col0 = lane & 15;
    const int g    = lane >> 4;

    float lg[8], lb[8], wv[8];
    #pragma unroll
    for (int t = 0; t < 8; ++t) {
        const int col = col0 + 16 * t;
        const float cb = bc[col];
        lg[t] = ln_g[col]; lb[t] = ln_b[col];
        if (FINAL) wv[t] = ow[col];
        #pragma unroll
        for (int r = 0; r < 4; ++r) acc[t][r] += cb;
    }

    #pragma unroll
    for (int r = 0; r < 4; ++r) {
        float s = 0.f, q = 0.f;
        #pragma unroll
        for (int t = 0; t < 8; ++t) { s += acc[t][r]; q += acc[t][r] * acc[t][r]; }
        #pragma unroll
        for (int off = 8; off > 0; off >>= 1) {
            s += __shfl_xor(s, off, 64);
            q += __shfl_xor(q, off, 64);
        }
        const float mean = s * (1.0f / H_DIM);
        const float var  = q * (1.0f / H_DIM) - mean * mean;
        const float rstd = rsqrtf(var + LN_EPS);
        const int row = base + wid * 16 + g * 4 + r;

        if (FINAL) {
            float dot = 0.f;
            #pragma unroll
            for (int t = 0; t < 8; ++t) {
                float o = (acc[t][r] - mean) * rstd * lg[t] + lb[t];
                dot += o * wv[t];
            }
            #pragma unroll
            for (int off = 8; off > 0; off >>= 1) dot += __shfl_xor(dot, off, 64);
            if (col0 == 0 && row < N_NODES) sout[row] = dot;
        } else {
            if (row < N_NODES) {
                #pragma unroll
                for (int t = 0; t < 8; ++t) {
                    float o = (acc[t][r] - mean) * rstd * lg[t] + lb[t];
                    if (RELU) o = fmaxf(o, 0.f);
                    hout[(size_t)row * H_DIM + col0 + 16 * t] = f2bf(o);
                }
            }
        }
    }
}

// ---------------------------------------------------------------------------
__device__ __forceinline__ float waveReduceSum(float v) {
    #pragma unroll
    for (int off = 32; off > 0; off >>= 1) v += __shfl_xor(v, off, 64);
    return v;
}

// per-graph mean over contiguous node range (batch sorted), plus out_b
__global__ void graph_mean_kernel(const float* __restrict__ s, const int* __restrict__ start,
                                  const float* __restrict__ ob, float* __restrict__ out) {
    const int g = blockIdx.x;
    const int lane = threadIdx.x;
    const int a = start[g], b = start[g + 1];
    float sum = 0.f;
    for (int i = a + lane; i < b; i += 64) sum += s[i];
    sum = waveReduceSum(sum);
    if (lane == 0) out[g] = sum / fmaxf((float)(b - a), 1.0f) + ob[0];
}

// ---------------------------------------------------------------------------
static inline size_t align256(size_t x) { return (x + 255) & ~(size_t)255; }

extern "C" void kernel_launch(void* const* d_in, const int* in_sizes, int n_in,
                              void* d_out, int out_size, void* d_ws, size_t ws_size,
                              hipStream_t stream) {
    const float* x        = (const float*)d_in[0];
    const int*   eidx     = (const int*)d_in[1];
    const int*   batch    = (const int*)d_in[2];
    const float* lin_l0_w = (const float*)d_in[3];
    const float* lin_l0_b = (const float*)d_in[4];
    const float* lin_r0_w = (const float*)d_in[5];
    const float* res0_w   = (const float*)d_in[6];
    const float* res0_b   = (const float*)d_in[7];
    const float* ln0_g    = (const float*)d_in[8];
    const float* ln0_b    = (const float*)d_in[9];
    const float* lin_l1_w = (const float*)d_in[10];
    const float* lin_l1_b = (const float*)d_in[11];
    const float* lin_r1_w = (const float*)d_in[12];
    const float* res1_w   = (const float*)d_in[13];
    const float* res1_b   = (const float*)d_in[14];
    const float* ln1_g    = (const float*)d_in[15];
    const float* ln1_b    = (const float*)d_in[16];
    const float* out_w    = (const float*)d_in[17];
    const float* out_b    = (const float*)d_in[18];
    float* out = (float*)d_out;

    const int* src = eidx;
    const int* dst = eidx + N_EDGES;

    // workspace layout
    char* p = (char*)d_ws;
    int*   binCnt = (int*)p;  p += align256(256 * 4);
    int2*  binned = (int2*)p; p += align256((size_t)NBINS * BINCAP * 8);
    int*   degv   = (int*)p;  p += align256((size_t)N_NODES * 4);
    int*   bucket = (int*)p;  p += align256((size_t)N_NODES * CAP * 4);
    int*   gstart = (int*)p;  p += align256((size_t)(N_GRAPHS + 1) * 4);
    u16*   xbf    = (u16*)p;  p += align256((size_t)N_NODES * F_IN * 2);
    u16*   h0bf   = (u16*)p;  p += align256((size_t)N_NODES * H_DIM * 2);
    u16*   aggbf  = (u16*)p;  p += align256((size_t)N_NODES * H_DIM * 2);
    float* snode  = (float*)p; p += align256((size_t)N_NODES * 4);
    u16*   W0p    = (u16*)p;  p += align256((size_t)(2 * F_IN) * H_DIM * 2);
    u16*   W1p    = (u16*)p;  p += align256((size_t)(2 * H_DIM) * H_DIM * 2);
    float* bcc    = (float*)p; p += align256(256 * 4);

    // fused prep (cvt + bias/binCnt + packw0 + packw1 + bounds) -- one launch
    prep_kernel<<<CVT_BLOCKS + 1 + PW0_BLOCKS + PW1_BLOCKS + BND_BLOCKS, 256, 0, stream>>>(
        x, xbf, lin_l0_b, res0_b, lin_l1_b, res1_b, bcc, binCnt,
        lin_l0_w, lin_r0_w, res0_w, W0p, lin_l1_w, lin_r1_w, res1_w, W1p,
        batch, gstart);

    // two-phase edge bucketing (replaces global-atomic fill)
    partition_kernel<<<(N_EDGES + CHUNK - 1) / CHUNK, 256, 0, stream>>>(src, dst, binCnt, binned);
    fillbin_kernel<<<NBINS, 256, 0, stream>>>(binned, binCnt, bucket, degv);

    const int nTiles = (N_NODES + 63) / 64;

    // layer 0
    gather_kernel<F_IN><<<(N_NODES * 64 + 255) / 256, 256, 0, stream>>>(xbf, bucket, degv, aggbf);
    layer_mfma_kernel<F_IN, true, false><<<nTiles, 256, 0, stream>>>(
        aggbf, xbf, W0p, bcc, ln0_g, ln0_b, nullptr, h0bf, nullptr);

    // layer 1 (fused with out_w dot -> per-node scalar)
    gather_kernel<H_DIM><<<(N_NODES * 64 + 255) / 256, 256, 0, stream>>>(h0bf, bucket, degv, aggbf);
    layer_mfma_kernel<H_DIM, false, true><<<nTiles, 256, 0, stream>>>(
        aggbf, h0bf, W1p, bcc + 128, ln1_g, ln1_b, out_w, nullptr, snode);

    // per-graph mean + bias
    graph_mean_kernel<<<N_GRAPHS, 64, 0, stream>>>(snode, gstart, out_b, out);
}

// Round 8
// 134.025 us; speedup vs baseline: 17.7405x; 1.0411x over previous
//
#include <hip/hip_runtime.h>

#define N_NODES 50000
#define N_EDGES 800000
#define F_IN    64
#define H_DIM   128
#define N_GRAPHS 512
#define LN_EPS  1e-5f
#define CAP     64          // max in-degree bucket capacity (Poisson(16): P(deg>=64) ~ 1e-20)
#define NBINS   196         // ceil(50000/256) -- bin = dst >> 8
#define BINCAP  5120        // edges per bin region (E[bin]=4096, 16 sigma headroom)
#define CHUNK   4096        // edges per partition block

typedef short  short8 __attribute__((ext_vector_type(8)));
typedef float  f32x4  __attribute__((ext_vector_type(4)));
typedef unsigned short u16;
typedef unsigned int   u32;

__device__ __forceinline__ float bf2f(u16 u) {
    u32 b = ((u32)u) << 16;
    return __builtin_bit_cast(float, b);
}
__device__ __forceinline__ u16 f2bf(float f) {   // round-to-nearest-even
    u32 b = __builtin_bit_cast(u32, f);
    return (u16)((b + 0x7FFFu + ((b >> 16) & 1u)) >> 16);
}

// ---------------------------------------------------------------------------
// pack weights into MFMA B-fragment order, bf16 (device helper).
// Logical W' [2K x 128]: rows 0..K-1 = Wl, rows K..2K-1 = Wr + Rw.
__device__ __forceinline__ void packw_body(const float* __restrict__ Wl,
                                           const float* __restrict__ Wr,
                                           const float* __restrict__ Rw,
                                           u16* __restrict__ out, int K, int tid) {
    int lane = tid & 63;
    int tile = (tid >> 6) & 7;
    int kstep = tid >> 9;
    int col = tile * 16 + (lane & 15);
    short8 o;
    #pragma unroll
    for (int e = 0; e < 8; ++e) {
        int k = kstep * 32 + (lane >> 4) * 8 + e;
        float v = (k < K) ? Wl[(size_t)k * H_DIM + col]
                          : (Wr[(size_t)(k - K) * H_DIM + col] + Rw[(size_t)(k - K) * H_DIM + col]);
        o[e] = (short)f2bf(v);
    }
    *reinterpret_cast<short8*>(&out[(size_t)tid * 8]) = o;
}

// ---------------------------------------------------------------------------
// fused prep: cvt(x->bf16) | bias-combine+binCnt-zero | packw0 | packw1 | bounds
#define CVT_BLOCKS   3125     // 50000*64/4 / 256
#define PW0_BLOCKS   8        // 2048 threads
#define PW1_BLOCKS   16       // 4096 threads
#define BND_BLOCKS   196      // ceil(50000/256)
__launch_bounds__(256)
__global__ void prep_kernel(const float* __restrict__ x, u16* __restrict__ xbf,
                            const float* __restrict__ l0b, const float* __restrict__ r0b,
                            const float* __restrict__ l1b, const float* __restrict__ r1b,
                            float* __restrict__ bcc, int* __restrict__ binCnt,
                            const float* __restrict__ Wl0, const float* __restrict__ Wr0,
                            const float* __restrict__ Rw0, u16* __restrict__ W0p,
                            const float* __restrict__ Wl1, const float* __restrict__ Wr1,
                            const float* __restrict__ Rw1, u16* __restrict__ W1p,
                            const int* __restrict__ batch, int* __restrict__ gstart) {
    const int b = blockIdx.x;
    const int tid = threadIdx.x;
    if (b < CVT_BLOCKS) {
        int i = b * 256 + tid;                       // < 800000 exactly
        float4 v = reinterpret_cast<const float4*>(x)[i];
        ushort4 o;
        o.x = f2bf(v.x); o.y = f2bf(v.y); o.z = f2bf(v.z); o.w = f2bf(v.w);
        reinterpret_cast<ushort4*>(xbf)[i] = o;
    } else if (b == CVT_BLOCKS) {
        if (tid < 128) {
            bcc[tid]       = l0b[tid] + r0b[tid];
            bcc[128 + tid] = l1b[tid] + r1b[tid];
            binCnt[tid] = 0;
            binCnt[128 + tid] = 0;
        }
    } else if (b < CVT_BLOCKS + 1 + PW0_BLOCKS) {
        packw_body(Wl0, Wr0, Rw0, W0p, F_IN, (b - CVT_BLOCKS - 1) * 256 + tid);
    } else if (b < CVT_BLOCKS + 1 + PW0_BLOCKS + PW1_BLOCKS) {
        packw_body(Wl1, Wr1, Rw1, W1p, H_DIM, (b - CVT_BLOCKS - 1 - PW0_BLOCKS) * 256 + tid);
    } else {
        int i = (b - CVT_BLOCKS - 1 - PW0_BLOCKS - PW1_BLOCKS) * 256 + tid;
        if (i >= N_NODES) return;
        int bb = batch[i];
        int prev = (i == 0) ? -1 : batch[i - 1];
        for (int g = prev + 1; g <= bb; ++g) gstart[g] = i;
        if (i == N_NODES - 1)
            for (int g = bb + 1; g <= N_GRAPHS; ++g) gstart[g] = N_NODES;
    }
}

// ---------------------------------------------------------------------------
// Phase 1: partition edges into NBINS coarse bins (bin = dst>>8), coalesced runs.
__launch_bounds__(256)
__global__ void partition_kernel(const int* __restrict__ src, const int* __restrict__ dst,
                                 int* __restrict__ binCnt, int2* __restrict__ binned) {
    __shared__ int2 lbuf[CHUNK];
    __shared__ int sHist[256];
    __shared__ int sScan[256];
    __shared__ int sCur[256];
    __shared__ int sGBase[256];
    const int tid = threadIdx.x;
    const int base = blockIdx.x * CHUNK;
    const int cnt = min(CHUNK, N_EDGES - base);

    // load up to 16 edges/thread into registers (coalesced)
    int2 ed[16];
    int nb[16];
    #pragma unroll
    for (int i = 0; i < 16; ++i) {
        int idx = base + i * 256 + tid;
        if (idx < N_EDGES) { ed[i].x = src[idx]; ed[i].y = dst[idx]; nb[i] = ed[i].y >> 8; }
        else nb[i] = -1;
    }
    sHist[tid] = 0;
    __syncthreads();
    #pragma unroll
    for (int i = 0; i < 16; ++i) if (nb[i] >= 0) atomicAdd(&sHist[nb[i]], 1);
    __syncthreads();

    // inclusive Hillis-Steele scan over 256
    sScan[tid] = sHist[tid];
    __syncthreads();
    for (int off = 1; off < 256; off <<= 1) {
        int v = sScan[tid];
        int add = (tid >= off) ? sScan[tid - off] : 0;
        __syncthreads();
        sScan[tid] = v + add;
        __syncthreads();
    }
    int excl = sScan[tid] - sHist[tid];
    __syncthreads();
    sScan[tid] = excl;           // exclusive scan, kept for copy-out
    sCur[tid]  = excl;           // atomic cursor for LDS reorder
    if (tid < NBINS && sHist[tid] > 0)
        sGBase[tid] = atomicAdd(&binCnt[tid], sHist[tid]);   // reserve global range
    __syncthreads();

    // reorder chunk into LDS, grouped by bin
    #pragma unroll
    for (int i = 0; i < 16; ++i) {
        if (nb[i] >= 0) {
            int p = atomicAdd(&sCur[nb[i]], 1);
            lbuf[p] = ed[i];
        }
    }
    __syncthreads();

    // copy out: consecutive t within a bin-run -> consecutive global slots
    for (int t = tid; t < cnt; t += 256) {
        int2 e = lbuf[t];
        int b = e.y >> 8;
        int slot = sGBase[b] + (t - sScan[b]);
        if (slot < BINCAP) binned[(size_t)b * BINCAP + slot] = e;
    }
}

// ---------------------------------------------------------------------------
// Phase 2: per-bin bucket fill; per-node cursors in LDS, bucket region L2-hot.
__launch_bounds__(256)
__global__ void fillbin_kernel(const int2* __restrict__ binned, const int* __restrict__ binCnt,
                               int* __restrict__ bucket, int* __restrict__ degv) {
    __shared__ int lcur[256];
    const int b = blockIdx.x;
    const int tid = threadIdx.x;
    const int nodeBase = b << 8;
    lcur[tid] = 0;
    __syncthreads();
    int cnt = binCnt[b];
    if (cnt > BINCAP) cnt = BINCAP;
    const int2* be = &binned[(size_t)b * BINCAP];
    for (int t = tid; t < cnt; t += 256) {
        int2 e = be[t];
        int pos = atomicAdd(&lcur[e.y & 255], 1);
        if (pos < CAP) bucket[(size_t)e.y * CAP + pos] = e.x;
    }
    __syncthreads();
    int node = nodeBase + tid;
    if (node < N_NODES) degv[node] = lcur[tid];
}

// ---------------------------------------------------------------------------
// gather-aggregate (bf16 in, bf16 out, fp32 accumulate, mean applied here).
// src row indices are wave-uniform -> readfirstlane forces SGPR row bases so
// row loads compile to global_load(v_lane_off, s[base]) with zero per-edge
// VALU address math (gather was ~60% VALUBusy before).
template <int K>
__launch_bounds__(256)
__global__ void gather_kernel(const u16* __restrict__ h, const int* __restrict__ bucket,
                              const int* __restrict__ degv, u16* __restrict__ agg) {
    const int node = (blockIdx.x * blockDim.x + threadIdx.x) >> 6;
    const int lane = threadIdx.x & 63;
    if (node >= N_NODES) return;
    int dg = degv[node];
    int dgc = dg > CAP ? CAP : dg;
    const int* bk = &bucket[(size_t)node * CAP];
    const int lane2 = lane * 2;

    float a0[8], a1[8];
    #pragma unroll
    for (int u = 0; u < 8; ++u) { a0[u] = 0.f; a1[u] = 0.f; }

    int e = 0;
    for (; e + 8 <= dgc; e += 8) {
        int4 q0 = *reinterpret_cast<const int4*>(&bk[e]);
        int4 q1 = *reinterpret_cast<const int4*>(&bk[e + 4]);
        int s[8];
        s[0] = __builtin_amdgcn_readfirstlane(q0.x);
        s[1] = __builtin_amdgcn_readfirstlane(q0.y);
        s[2] = __builtin_amdgcn_readfirstlane(q0.z);
        s[3] = __builtin_amdgcn_readfirstlane(q0.w);
        s[4] = __builtin_amdgcn_readfirstlane(q1.x);
        s[5] = __builtin_amdgcn_readfirstlane(q1.y);
        s[6] = __builtin_amdgcn_readfirstlane(q1.z);
        s[7] = __builtin_amdgcn_readfirstlane(q1.w);
        if constexpr (K == 128) {
            u32 w[8];
            #pragma unroll
            for (int u = 0; u < 8; ++u)
                w[u] = *reinterpret_cast<const u32*>(h + (size_t)s[u] * K + lane2);
            #pragma unroll
            for (int u = 0; u < 8; ++u) {
                a0[u] += bf2f((u16)w[u]);
                a1[u] += bf2f((u16)(w[u] >> 16));
            }
        } else {
            u16 w[8];
            #pragma unroll
            for (int u = 0; u < 8; ++u) w[u] = *(h + (size_t)s[u] * K + lane);
            #pragma unroll
            for (int u = 0; u < 8; ++u) a0[u] += bf2f(w[u]);
        }
    }
    // tail: fixed accumulator slots (no runtime indexing)
    {
        int rem = dgc - e;
        #pragma unroll
        for (int u = 0; u < 7; ++u) {
            if (u < rem) {
                int s = __builtin_amdgcn_readfirstlane(bk[e + u]);
                if constexpr (K == 128) {
                    u32 w = *reinterpret_cast<const u32*>(h + (size_t)s * K + lane2);
                    a0[u] += bf2f((u16)w);
                    a1[u] += bf2f((u16)(w >> 16));
                } else {
                    a0[u] += bf2f(*(h + (size_t)s * K + lane));
                }
            }
        }
    }
    const float invd = 1.0f / fmaxf((float)dg, 1.0f);
    const float s0 = (((a0[0] + a0[1]) + (a0[2] + a0[3])) + ((a0[4] + a0[5]) + (a0[6] + a0[7]))) * invd;
    if constexpr (K == 128) {
        const float s1 = (((a1[0] + a1[1]) + (a1[2] + a1[3])) + ((a1[4] + a1[5]) + (a1[6] + a1[7]))) * invd;
        u32 o = (u32)f2bf(s0) | ((u32)f2bf(s1) << 16);
        *reinterpret_cast<u32*>(&agg[(size_t)node * K + lane2]) = o;
    } else {
        agg[(size_t)node * K + lane] = f2bf(s0);
    }
}

// ---------------------------------------------------------------------------
// fused MFMA layer: pre = [agg | hin] @ [Wl ; Wc] + bc ; t = LN(pre)
//   FINAL=false: hout = (RELU ? relu(t) : t) as bf16 [N,128]
//   FINAL=true : sout[node] = t . ow  (fp32 scalar)
template <int K, bool RELU, bool FINAL>
__launch_bounds__(256)
__global__ void layer_mfma_kernel(const u16* __restrict__ aggbf,   // [N,K] (invd applied)
                                  const u16* __restrict__ hbf,     // [N,K]
                                  const u16* __restrict__ Wpack,   // fragment-ordered
                                  const float* __restrict__ bc,    // [128]
                                  const float* __restrict__ ln_g,  // [128]
                                  const float* __restrict__ ln_b,  // [128]
                                  const float* __restrict__ ow,    // [128] (FINAL)
                                  u16* __restrict__ hout,          // [N,128] (non-FINAL)
                                  float* __restrict__ sout) {      // [N]     (FINAL)
    constexpr int K2   = 2 * K;
    constexpr int NKS  = K2 / 32;     // MFMA k-steps
    constexpr int ROWB = K2 * 2;      // bytes per LDS row
    constexpr int CPR  = ROWB / 16;   // 16B chunks per row
    __shared__ __align__(16) char sA[64 * ROWB];

    const int tid  = threadIdx.x;
    const int lane = tid & 63;
    const int wid  = tid >> 6;
    const int base = blockIdx.x * 64;

    // ---- stage A tile (cols 0..K-1 = agg, K..2K-1 = hin), coalesced 16B ----
    for (int c = tid; c < 64 * CPR; c += 256) {
        int row = c / CPR, c16 = c % CPR;
        int rg = base + row; if (rg >= N_NODES) rg = N_NODES - 1;
        const u16* srcp = (c16 < CPR / 2) ? &aggbf[(size_t)rg * K + c16 * 8]
                                          : &hbf[(size_t)rg * K + (c16 - CPR / 2) * 8];
        float4 v = *reinterpret_cast<const float4*>(srcp);
        *reinterpret_cast<float4*>(&sA[row * ROWB + ((c16 * 16) ^ ((row & 7) << 4))]) = v;
    }
    __syncthreads();

    // ---- MFMA accumulate: 8 col-tiles of 16, rows = wave's 16 ----
    f32x4 acc[8];
    #pragma unroll
    for (int t = 0; t < 8; ++t) acc[t] = (f32x4){0.f, 0.f, 0.f, 0.f};

    const int arow = lane & 15;
    const int kg   = lane >> 4;
    const int lrow = wid * 16 + arow;               // LDS row
    #pragma unroll
    for (int ks = 0; ks < NKS; ++ks) {
        short8 af = *reinterpret_cast<const short8*>(
            &sA[lrow * ROWB + (((ks * 64 + kg * 16)) ^ ((lrow & 7) << 4))]);
        #pragma unroll
        for (int t = 0; t < 8; ++t) {
            short8 bf = *reinterpret_cast<const short8*>(&Wpack[(size_t)((ks * 8 + t) * 64 + lane) * 8]);
            acc[t] = __builtin_amdgcn_mfma_f32_16x16x32_bf16(af, bf, acc[t], 0, 0, 0);
        }
    }

    // ---- epilogue: +bias, LayerNorm per row (16-lane reduce), output ----
    // C layout: col = (lane&15) + 16*t ; row = wid*16 + (lane>>4)*4 + reg
    const int col0 = lane & 15;
    const int g    = lane >> 4;

    float lg[8], lb[8], wv[8];
    #pragma unroll
    for (int t = 0; t < 8; ++t) {
        const int col = col0 + 16 * t;
        const float cb = bc[col];
        lg[t] = ln_g[col]; lb[t] = ln_b[col];
        if (FINAL) wv[t] = ow[col];
        #pragma unroll
        for (int r = 0; r < 4; ++r) acc[t][r] += cb;
    }

    #pragma unroll
    for (int r = 0; r < 4; ++r) {
        float s = 0.f, q = 0.f;
        #pragma unroll
        for (int t = 0; t < 8; ++t) { s += acc[t][r]; q += acc[t][r] * acc[t][r]; }
        #pragma unroll
        for (int off = 8; off > 0; off >>= 1) {
            s += __shfl_xor(s, off, 64);
            q += __shfl_xor(q, off, 64);
        }
        const float mean = s * (1.0f / H_DIM);
        const float var  = q * (1.0f / H_DIM) - mean * mean;
        const float rstd = rsqrtf(var + LN_EPS);
        const int row = base + wid * 16 + g * 4 + r;

        if (FINAL) {
            float dot = 0.f;
            #pragma unroll
            for (int t = 0; t < 8; ++t) {
                float o = (acc[t][r] - mean) * rstd * lg[t] + lb[t];
                dot += o * wv[t];
            }
            #pragma unroll
            for (int off = 8; off > 0; off >>= 1) dot += __shfl_xor(dot, off, 64);
            if (col0 == 0 && row < N_NODES) sout[row] = dot;
        } else {
            if (row < N_NODES) {
                #pragma unroll
                for (int t = 0; t < 8; ++t) {
                    float o = (acc[t][r] - mean) * rstd * lg[t] + lb[t];
                    if (RELU) o = fmaxf(o, 0.f);
                    hout[(size_t)row * H_DIM + col0 + 16 * t] = f2bf(o);
                }
            }
        }
    }
}

// ---------------------------------------------------------------------------
__device__ __forceinline__ float waveReduceSum(float v) {
    #pragma unroll
    for (int off = 32; off > 0; off >>= 1) v += __shfl_xor(v, off, 64);
    return v;
}

// per-graph mean over contiguous node range (batch sorted), plus out_b
__global__ void graph_mean_kernel(const float* __restrict__ s, const int* __restrict__ start,
                                  const float* __restrict__ ob, float* __restrict__ out) {
    const int g = blockIdx.x;
    const int lane = threadIdx.x;
    const int a = start[g], b = start[g + 1];
    float sum = 0.f;
    for (int i = a + lane; i < b; i += 64) sum += s[i];
    sum = waveReduceSum(sum);
    if (lane == 0) out[g] = sum / fmaxf((float)(b - a), 1.0f) + ob[0];
}

// ---------------------------------------------------------------------------
static inline size_t align256(size_t x) { return (x + 255) & ~(size_t)255; }

extern "C" void kernel_launch(void* const* d_in, const int* in_sizes, int n_in,
                              void* d_out, int out_size, void* d_ws, size_t ws_size,
                              hipStream_t stream) {
    const float* x        = (const float*)d_in[0];
    const int*   eidx     = (const int*)d_in[1];
    const int*   batch    = (const int*)d_in[2];
    const float* lin_l0_w = (const float*)d_in[3];
    const float* lin_l0_b = (const float*)d_in[4];
    const float* lin_r0_w = (const float*)d_in[5];
    const float* res0_w   = (const float*)d_in[6];
    const float* res0_b   = (const float*)d_in[7];
    const float* ln0_g    = (const float*)d_in[8];
    const float* ln0_b    = (const float*)d_in[9];
    const float* lin_l1_w = (const float*)d_in[10];
    const float* lin_l1_b = (const float*)d_in[11];
    const float* lin_r1_w = (const float*)d_in[12];
    const float* res1_w   = (const float*)d_in[13];
    const float* res1_b   = (const float*)d_in[14];
    const float* ln1_g    = (const float*)d_in[15];
    const float* ln1_b    = (const float*)d_in[16];
    const float* out_w    = (const float*)d_in[17];
    const float* out_b    = (const float*)d_in[18];
    float* out = (float*)d_out;

    const int* src = eidx;
    const int* dst = eidx + N_EDGES;

    // workspace layout
    char* p = (char*)d_ws;
    int*   binCnt = (int*)p;  p += align256(256 * 4);
    int2*  binned = (int2*)p; p += align256((size_t)NBINS * BINCAP * 8);
    int*   degv   = (int*)p;  p += align256((size_t)N_NODES * 4);
    int*   bucket = (int*)p;  p += align256((size_t)N_NODES * CAP * 4);
    int*   gstart = (int*)p;  p += align256((size_t)(N_GRAPHS + 1) * 4);
    u16*   xbf    = (u16*)p;  p += align256((size_t)N_NODES * F_IN * 2);
    u16*   h0bf   = (u16*)p;  p += align256((size_t)N_NODES * H_DIM * 2);
    u16*   aggbf  = (u16*)p;  p += align256((size_t)N_NODES * H_DIM * 2);
    float* snode  = (float*)p; p += align256((size_t)N_NODES * 4);
    u16*   W0p    = (u16*)p;  p += align256((size_t)(2 * F_IN) * H_DIM * 2);
    u16*   W1p    = (u16*)p;  p += align256((size_t)(2 * H_DIM) * H_DIM * 2);
    float* bcc    = (float*)p; p += align256(256 * 4);

    // fused prep (cvt + bias/binCnt + packw0 + packw1 + bounds) -- one launch
    prep_kernel<<<CVT_BLOCKS + 1 + PW0_BLOCKS + PW1_BLOCKS + BND_BLOCKS, 256, 0, stream>>>(
        x, xbf, lin_l0_b, res0_b, lin_l1_b, res1_b, bcc, binCnt,
        lin_l0_w, lin_r0_w, res0_w, W0p, lin_l1_w, lin_r1_w, res1_w, W1p,
        batch, gstart);

    // two-phase edge bucketing (replaces global-atomic fill)
    partition_kernel<<<(N_EDGES + CHUNK - 1) / CHUNK, 256, 0, stream>>>(src, dst, binCnt, binned);
    fillbin_kernel<<<NBINS, 256, 0, stream>>>(binned, binCnt, bucket, degv);

    const int nTiles = (N_NODES + 63) / 64;

    // layer 0
    gather_kernel<F_IN><<<(N_NODES * 64 + 255) / 256, 256, 0, stream>>>(xbf, bucket, degv, aggbf);
    layer_mfma_kernel<F_IN, true, false><<<nTiles, 256, 0, stream>>>(
        aggbf, xbf, W0p, bcc, ln0_g, ln0_b, nullptr, h0bf, nullptr);

    // layer 1 (fused with out_w dot -> per-node scalar)
    gather_kernel<H_DIM><<<(N_NODES * 64 + 255) / 256, 256, 0, stream>>>(h0bf, bucket, degv, aggbf);
    layer_mfma_kernel<H_DIM, false, true><<<nTiles, 256, 0, stream>>>(
        aggbf, h0bf, W1p, bcc + 128, ln1_g, ln1_b, out_w, nullptr, snode);

    // per-graph mean + bias
    graph_mean_kernel<<<N_GRAPHS, 64, 0, stream>>>(snode, gstart, out_b, out);
}

// Round 9
// 130.483 us; speedup vs baseline: 18.2221x; 1.0271x over previous
//
#include <hip/hip_runtime.h>

#define N_NODES 50000
#define N_EDGES 800000
#define F_IN    64
#define H_DIM   128
#define N_GRAPHS 512
#define LN_EPS  1e-5f
#define CAP     64          // max in-degree bucket capacity (Poisson(16): P(deg>=64) ~ 1e-20)
#define NBINS   196         // ceil(50000/256) -- bin = dst >> 8
#define BINCAP  5120        // edges per bin region (E[bin]=4096, 16 sigma headroom)
#define CHUNK   2048        // edges per partition block (391 blocks ~ 1.5/CU)

typedef short  short8 __attribute__((ext_vector_type(8)));
typedef float  f32x4  __attribute__((ext_vector_type(4)));
typedef unsigned short u16;
typedef unsigned int   u32;

__device__ __forceinline__ float bf2f(u16 u) {
    u32 b = ((u32)u) << 16;
    return __builtin_bit_cast(float, b);
}
__device__ __forceinline__ u16 f2bf(float f) {   // round-to-nearest-even
    u32 b = __builtin_bit_cast(u32, f);
    return (u16)((b + 0x7FFFu + ((b >> 16) & 1u)) >> 16);
}

// ---------------------------------------------------------------------------
// pack weights into MFMA B-fragment order, bf16 (device helper).
__device__ __forceinline__ void packw_body(const float* __restrict__ Wl,
                                           const float* __restrict__ Wr,
                                           const float* __restrict__ Rw,
                                           u16* __restrict__ out, int K, int tid) {
    int lane = tid & 63;
    int tile = (tid >> 6) & 7;
    int kstep = tid >> 9;
    int col = tile * 16 + (lane & 15);
    short8 o;
    #pragma unroll
    for (int e = 0; e < 8; ++e) {
        int k = kstep * 32 + (lane >> 4) * 8 + e;
        float v = (k < K) ? Wl[(size_t)k * H_DIM + col]
                          : (Wr[(size_t)(k - K) * H_DIM + col] + Rw[(size_t)(k - K) * H_DIM + col]);
        o[e] = (short)f2bf(v);
    }
    *reinterpret_cast<short8*>(&out[(size_t)tid * 8]) = o;
}

// ---------------------------------------------------------------------------
// fused prep: cvt(x->bf16) | bias-combine+binCnt-zero | packw0 | packw1 | bounds
#define CVT_BLOCKS   3125     // 50000*64/4 / 256
#define PW0_BLOCKS   8
#define PW1_BLOCKS   16
#define BND_BLOCKS   196
__launch_bounds__(256)
__global__ void prep_kernel(const float* __restrict__ x, u16* __restrict__ xbf,
                            const float* __restrict__ l0b, const float* __restrict__ r0b,
                            const float* __restrict__ l1b, const float* __restrict__ r1b,
                            float* __restrict__ bcc, int* __restrict__ binCnt,
                            const float* __restrict__ Wl0, const float* __restrict__ Wr0,
                            const float* __restrict__ Rw0, u16* __restrict__ W0p,
                            const float* __restrict__ Wl1, const float* __restrict__ Wr1,
                            const float* __restrict__ Rw1, u16* __restrict__ W1p,
                            const int* __restrict__ batch, int* __restrict__ gstart) {
    const int b = blockIdx.x;
    const int tid = threadIdx.x;
    if (b < CVT_BLOCKS) {
        int i = b * 256 + tid;
        float4 v = reinterpret_cast<const float4*>(x)[i];
        ushort4 o;
        o.x = f2bf(v.x); o.y = f2bf(v.y); o.z = f2bf(v.z); o.w = f2bf(v.w);
        reinterpret_cast<ushort4*>(xbf)[i] = o;
    } else if (b == CVT_BLOCKS) {
        if (tid < 128) {
            bcc[tid]       = l0b[tid] + r0b[tid];
            bcc[128 + tid] = l1b[tid] + r1b[tid];
            binCnt[tid] = 0;
            binCnt[128 + tid] = 0;
        }
    } else if (b < CVT_BLOCKS + 1 + PW0_BLOCKS) {
        packw_body(Wl0, Wr0, Rw0, W0p, F_IN, (b - CVT_BLOCKS - 1) * 256 + tid);
    } else if (b < CVT_BLOCKS + 1 + PW0_BLOCKS + PW1_BLOCKS) {
        packw_body(Wl1, Wr1, Rw1, W1p, H_DIM, (b - CVT_BLOCKS - 1 - PW0_BLOCKS) * 256 + tid);
    } else {
        int i = (b - CVT_BLOCKS - 1 - PW0_BLOCKS - PW1_BLOCKS) * 256 + tid;
        if (i >= N_NODES) return;
        int bb = batch[i];
        int prev = (i == 0) ? -1 : batch[i - 1];
        for (int g = prev + 1; g <= bb; ++g) gstart[g] = i;
        if (i == N_NODES - 1)
            for (int g = bb + 1; g <= N_GRAPHS; ++g) gstart[g] = N_NODES;
    }
}

// ---------------------------------------------------------------------------
// Phase 1: partition edges into NBINS coarse bins (bin = dst>>8).
// ushort2 edge records (node ids < 65536); shfl wave-scan (2 barriers not 16).
#define EPT (CHUNK / 256)    // edges per thread = 8
__launch_bounds__(256)
__global__ void partition_kernel(const int* __restrict__ src, const int* __restrict__ dst,
                                 int* __restrict__ binCnt, ushort2* __restrict__ binned) {
    __shared__ ushort2 lbuf[CHUNK];          // 8 KB
    __shared__ int sHist[256];
    __shared__ int sScan[256];
    __shared__ int sCur[256];
    __shared__ int sGBase[256];
    __shared__ int sWS[4];
    const int tid = threadIdx.x;
    const int base = blockIdx.x * CHUNK;
    const int cnt = min(CHUNK, N_EDGES - base);

    int es[EPT], ed[EPT], nb[EPT];
    #pragma unroll
    for (int i = 0; i < EPT; ++i) {
        int idx = base + i * 256 + tid;
        if (idx < N_EDGES) { es[i] = src[idx]; ed[i] = dst[idx]; nb[i] = ed[i] >> 8; }
        else nb[i] = -1;
    }
    sHist[tid] = 0;
    __syncthreads();
    #pragma unroll
    for (int i = 0; i < EPT; ++i) if (nb[i] >= 0) atomicAdd(&sHist[nb[i]], 1);
    __syncthreads();

    // scan: shfl-based inclusive scan within wave, then cross-wave combine
    int v = sHist[tid];
    int pv = v;
    #pragma unroll
    for (int off = 1; off < 64; off <<= 1) {
        int t = __shfl_up(pv, off, 64);
        if ((tid & 63) >= off) pv += t;
    }
    if ((tid & 63) == 63) sWS[tid >> 6] = pv;
    __syncthreads();
    int wadd = 0;
    #pragma unroll
    for (int wg = 0; wg < 4; ++wg) if (wg < (tid >> 6)) wadd += sWS[wg];
    int excl = pv + wadd - v;
    sScan[tid] = excl;
    sCur[tid]  = excl;
    if (tid < NBINS && v > 0)
        sGBase[tid] = atomicAdd(&binCnt[tid], v);
    __syncthreads();

    // reorder chunk into LDS, grouped by bin
    #pragma unroll
    for (int i = 0; i < EPT; ++i) {
        if (nb[i] >= 0) {
            int p = atomicAdd(&sCur[nb[i]], 1);
            ushort2 t; t.x = (u16)es[i]; t.y = (u16)ed[i];
            lbuf[p] = t;
        }
    }
    __syncthreads();

    // copy out: consecutive t within a bin-run -> consecutive global slots
    for (int t = tid; t < cnt; t += 256) {
        ushort2 e = lbuf[t];
        int b = e.y >> 8;
        int slot = sGBase[b] + (t - sScan[b]);
        if (slot < BINCAP) binned[(size_t)b * BINCAP + slot] = e;
    }
}

// ---------------------------------------------------------------------------
// Phase 2: per-bin bucket fill (u16 bucket); per-node cursors in LDS.
__launch_bounds__(256)
__global__ void fillbin_kernel(const ushort2* __restrict__ binned, const int* __restrict__ binCnt,
                               u16* __restrict__ bucket, int* __restrict__ degv) {
    __shared__ int lcur[256];
    const int b = blockIdx.x;
    const int tid = threadIdx.x;
    const int nodeBase = b << 8;
    lcur[tid] = 0;
    __syncthreads();
    int cnt = binCnt[b];
    if (cnt > BINCAP) cnt = BINCAP;
    const ushort2* be = &binned[(size_t)b * BINCAP];
    for (int t = tid; t < cnt; t += 256) {
        ushort2 e = be[t];
        int d = e.y;
        int pos = atomicAdd(&lcur[d & 255], 1);
        if (pos < CAP) bucket[(size_t)d * CAP + pos] = e.x;
    }
    __syncthreads();
    int node = nodeBase + tid;
    if (node < N_NODES) degv[node] = lcur[tid];
}

// ---------------------------------------------------------------------------
// gather-aggregate: 16-deep ILP (16 outstanding row loads/wave), SGPR row bases
// via readfirstlane on packed u16 index pairs.
template <int K>
__launch_bounds__(256)
__global__ void gather_kernel(const u16* __restrict__ h, const u16* __restrict__ bucket,
                              const int* __restrict__ degv, u16* __restrict__ agg) {
    const int node = (blockIdx.x * blockDim.x + threadIdx.x) >> 6;
    const int lane = threadIdx.x & 63;
    if (node >= N_NODES) return;
    int dg = degv[node];
    int dgc = dg > CAP ? CAP : dg;
    const u16* bk = &bucket[(size_t)node * CAP];
    const int lane2 = lane * 2;

    float a0[8], a1[8];
    #pragma unroll
    for (int u = 0; u < 8; ++u) { a0[u] = 0.f; a1[u] = 0.f; }

    int e = 0;
    // ---- 16-edge main loop: 16 loads in flight ----
    for (; e + 16 <= dgc; e += 16) {
        int4 qa = *reinterpret_cast<const int4*>(&bk[e]);        // 8 u16 idx
        int4 qb = *reinterpret_cast<const int4*>(&bk[e + 8]);    // 8 u16 idx
        u32 p[8];
        p[0] = (u32)__builtin_amdgcn_readfirstlane(qa.x);
        p[1] = (u32)__builtin_amdgcn_readfirstlane(qa.y);
        p[2] = (u32)__builtin_amdgcn_readfirstlane(qa.z);
        p[3] = (u32)__builtin_amdgcn_readfirstlane(qa.w);
        p[4] = (u32)__builtin_amdgcn_readfirstlane(qb.x);
        p[5] = (u32)__builtin_amdgcn_readfirstlane(qb.y);
        p[6] = (u32)__builtin_amdgcn_readfirstlane(qb.z);
        p[7] = (u32)__builtin_amdgcn_readfirstlane(qb.w);
        if constexpr (K == 128) {
            u32 w[16];
            #pragma unroll
            for (int u = 0; u < 8; ++u) {
                w[2 * u]     = *reinterpret_cast<const u32*>(h + (size_t)(p[u] & 0xFFFFu) * K + lane2);
                w[2 * u + 1] = *reinterpret_cast<const u32*>(h + (size_t)(p[u] >> 16) * K + lane2);
            }
            #pragma unroll
            for (int u = 0; u < 8; ++u) {
                a0[u] += bf2f((u16)w[u]);        a1[u] += bf2f((u16)(w[u] >> 16));
                a0[u] += bf2f((u16)w[u + 8]);    a1[u] += bf2f((u16)(w[u + 8] >> 16));
            }
        } else {
            u16 w[16];
            #pragma unroll
            for (int u = 0; u < 8; ++u) {
                w[2 * u]     = *(h + (size_t)(p[u] & 0xFFFFu) * K + lane);
                w[2 * u + 1] = *(h + (size_t)(p[u] >> 16) * K + lane);
            }
            #pragma unroll
            for (int u = 0; u < 8; ++u) { a0[u] += bf2f(w[u]); a0[u] += bf2f(w[u + 8]); }
        }
    }
    // ---- 8-edge loop ----
    for (; e + 8 <= dgc; e += 8) {
        int4 qa = *reinterpret_cast<const int4*>(&bk[e]);
        u32 p[4];
        p[0] = (u32)__builtin_amdgcn_readfirstlane(qa.x);
        p[1] = (u32)__builtin_amdgcn_readfirstlane(qa.y);
        p[2] = (u32)__builtin_amdgcn_readfirstlane(qa.z);
        p[3] = (u32)__builtin_amdgcn_readfirstlane(qa.w);
        if constexpr (K == 128) {
            u32 w[8];
            #pragma unroll
            for (int u = 0; u < 4; ++u) {
                w[2 * u]     = *reinterpret_cast<const u32*>(h + (size_t)(p[u] & 0xFFFFu) * K + lane2);
                w[2 * u + 1] = *reinterpret_cast<const u32*>(h + (size_t)(p[u] >> 16) * K + lane2);
            }
            #pragma unroll
            for (int u = 0; u < 8; ++u) { a0[u] += bf2f((u16)w[u]); a1[u] += bf2f((u16)(w[u] >> 16)); }
        } else {
            u16 w[8];
            #pragma unroll
            for (int u = 0; u < 4; ++u) {
                w[2 * u]     = *(h + (size_t)(p[u] & 0xFFFFu) * K + lane);
                w[2 * u + 1] = *(h + (size_t)(p[u] >> 16) * K + lane);
            }
            #pragma unroll
            for (int u = 0; u < 8; ++u) a0[u] += bf2f(w[u]);
        }
    }
    // ---- tail: fixed accumulator slots, scalar idx ----
    {
        int rem = dgc - e;
        #pragma unroll
        for (int u = 0; u < 7; ++u) {
            if (u < rem) {
                int s = __builtin_amdgcn_readfirstlane((int)bk[e + u]);
                if constexpr (K == 128) {
                    u32 w = *reinterpret_cast<const u32*>(h + (size_t)s * K + lane2);
                    a0[u] += bf2f((u16)w);
                    a1[u] += bf2f((u16)(w >> 16));
                } else {
                    a0[u] += bf2f(*(h + (size_t)s * K + lane));
                }
            }
        }
    }
    const float invd = 1.0f / fmaxf((float)dg, 1.0f);
    const float s0 = (((a0[0] + a0[1]) + (a0[2] + a0[3])) + ((a0[4] + a0[5]) + (a0[6] + a0[7]))) * invd;
    if constexpr (K == 128) {
        const float s1 = (((a1[0] + a1[1]) + (a1[2] + a1[3])) + ((a1[4] + a1[5]) + (a1[6] + a1[7]))) * invd;
        u32 o = (u32)f2bf(s0) | ((u32)f2bf(s1) << 16);
        *reinterpret_cast<u32*>(&agg[(size_t)node * K + lane2]) = o;
    } else {
        agg[(size_t)node * K + lane] = f2bf(s0);
    }
}

// ---------------------------------------------------------------------------
// fused MFMA layer: pre = [agg | hin] @ [Wl ; Wc] + bc ; t = LN(pre)
template <int K, bool RELU, bool FINAL>
__launch_bounds__(256)
__global__ void layer_mfma_kernel(const u16* __restrict__ aggbf,
                                  const u16* __restrict__ hbf,
                                  const u16* __restrict__ Wpack,
                                  const float* __restrict__ bc,
                                  const float* __restrict__ ln_g,
                                  const float* __restrict__ ln_b,
                                  const float* __restrict__ ow,
                                  u16* __restrict__ hout,
                                  float* __restrict__ sout) {
    constexpr int K2   = 2 * K;
    constexpr int NKS  = K2 / 32;
    constexpr int ROWB = K2 * 2;
    constexpr int CPR  = ROWB / 16;
    __shared__ __align__(16) char sA[64 * ROWB];

    const int tid  = threadIdx.x;
    const int lane = tid & 63;
    const int wid  = tid >> 6;
    const int base = blockIdx.x * 64;

    for (int c = tid; c < 64 * CPR; c += 256) {
        int row = c / CPR, c16 = c % CPR;
        int rg = base + row; if (rg >= N_NODES) rg = N_NODES - 1;
        const u16* srcp = (c16 < CPR / 2) ? &aggbf[(size_t)rg * K + c16 * 8]
                                          : &hbf[(size_t)rg * K + (c16 - CPR / 2) * 8];
        float4 v = *reinterpret_cast<const float4*>(srcp);
        *reinterpret_cast<float4*>(&sA[row * ROWB + ((c16 * 16) ^ ((row & 7) << 4))]) = v;
    }
    __syncthreads();

    f32x4 acc[8];
    #pragma unroll
    for (int t = 0; t < 8; ++t) acc[t] = (f32x4){0.f, 0.f, 0.f, 0.f};

    const int arow = lane & 15;
    const int kg   = lane >> 4;
    const int lrow = wid * 16 + arow;
    #pragma unroll
    for (int ks = 0; ks < NKS; ++ks) {
        short8 af = *reinterpret_cast<const short8*>(
            &sA[lrow * ROWB + (((ks * 64 + kg * 16)) ^ ((lrow & 7) << 4))]);
        #pragma unroll
        for (int t = 0; t < 8; ++t) {
            short8 bf = *reinterpret_cast<const short8*>(&Wpack[(size_t)((ks * 8 + t) * 64 + lane) * 8]);
            acc[t] = __builtin_amdgcn_mfma_f32_16x16x32_bf16(af, bf, acc[t], 0, 0, 0);
        }
    }

    const int col0 = lane & 15;
    const int g    = lane >> 4;

    float lg[8], lb[8], wv[8];
    #pragma unroll
    for (int t = 0; t < 8; ++t) {
        const int col = col0 + 16 * t;
        const float cb = bc[col];
        lg[t] = ln_g[col]; lb[t] = ln_b[col];
        if (FINAL) wv[t] = ow[col];
        #pragma unroll
        for (int r = 0; r < 4; ++r) acc[t][r] += cb;
    }

    #pragma unroll
    for (int r = 0; r < 4; ++r) {
        float s = 0.f, q = 0.f;
        #pragma unroll
        for (int t = 0; t < 8; ++t) { s += acc[t][r]; q += acc[t][r] * acc[t][r]; }
        #pragma unroll
        for (int off = 8; off > 0; off >>= 1) {
            s += __shfl_xor(s, off, 64);
            q += __shfl_xor(q, off, 64);
        }
        const float mean = s * (1.0f / H_DIM);
        const float var  = q * (1.0f / H_DIM) - mean * mean;
        const float rstd = rsqrtf(var + LN_EPS);
        const int row = base + wid * 16 + g * 4 + r;

        if (FINAL) {
            float dot = 0.f;
            #pragma unroll
            for (int t = 0; t < 8; ++t) {
                float o = (acc[t][r] - mean) * rstd * lg[t] + lb[t];
                dot += o * wv[t];
            }
            #pragma unroll
            for (int off = 8; off > 0; off >>= 1) dot += __shfl_xor(dot, off, 64);
            if (col0 == 0 && row < N_NODES) sout[row] = dot;
        } else {
            if (row < N_NODES) {
                #pragma unroll
                for (int t = 0; t < 8; ++t) {
                    float o = (acc[t][r] - mean) * rstd * lg[t] + lb[t];
                    if (RELU) o = fmaxf(o, 0.f);
                    hout[(size_t)row * H_DIM + col0 + 16 * t] = f2bf(o);
                }
            }
        }
    }
}

// ---------------------------------------------------------------------------
__device__ __forceinline__ float waveReduceSum(float v) {
    #pragma unroll
    for (int off = 32; off > 0; off >>= 1) v += __shfl_xor(v, off, 64);
    return v;
}

__global__ void graph_mean_kernel(const float* __restrict__ s, const int* __restrict__ start,
                                  const float* __restrict__ ob, float* __restrict__ out) {
    const int g = blockIdx.x;
    const int lane = threadIdx.x;
    const int a = start[g], b = start[g + 1];
    float sum = 0.f;
    for (int i = a + lane; i < b; i += 64) sum += s[i];
    sum = waveReduceSum(sum);
    if (lane == 0) out[g] = sum / fmaxf((float)(b - a), 1.0f) + ob[0];
}

// ---------------------------------------------------------------------------
static inline size_t align256(size_t x) { return (x + 255) & ~(size_t)255; }

extern "C" void kernel_launch(void* const* d_in, const int* in_sizes, int n_in,
                              void* d_out, int out_size, void* d_ws, size_t ws_size,
                              hipStream_t stream) {
    const float* x        = (const float*)d_in[0];
    const int*   eidx     = (const int*)d_in[1];
    const int*   batch    = (const int*)d_in[2];
    const float* lin_l0_w = (const float*)d_in[3];
    const float* lin_l0_b = (const float*)d_in[4];
    const float* lin_r0_w = (const float*)d_in[5];
    const float* res0_w   = (const float*)d_in[6];
    const float* res0_b   = (const float*)d_in[7];
    const float* ln0_g    = (const float*)d_in[8];
    const float* ln0_b    = (const float*)d_in[9];
    const float* lin_l1_w = (const float*)d_in[10];
    const float* lin_l1_b = (const float*)d_in[11];
    const float* lin_r1_w = (const float*)d_in[12];
    const float* res1_w   = (const float*)d_in[13];
    const float* res1_b   = (const float*)d_in[14];
    const float* ln1_g    = (const float*)d_in[15];
    const float* ln1_b    = (const float*)d_in[16];
    const float* out_w    = (const float*)d_in[17];
    const float* out_b    = (const float*)d_in[18];
    float* out = (float*)d_out;

    const int* src = eidx;
    const int* dst = eidx + N_EDGES;

    // workspace layout
    char* p = (char*)d_ws;
    int*     binCnt = (int*)p;     p += align256(256 * 4);
    ushort2* binned = (ushort2*)p; p += align256((size_t)NBINS * BINCAP * 4);
    int*     degv   = (int*)p;     p += align256((size_t)N_NODES * 4);
    u16*     bucket = (u16*)p;     p += align256((size_t)N_NODES * CAP * 2);
    int*     gstart = (int*)p;     p += align256((size_t)(N_GRAPHS + 1) * 4);
    u16*     xbf    = (u16*)p;     p += align256((size_t)N_NODES * F_IN * 2);
    u16*     h0bf   = (u16*)p;     p += align256((size_t)N_NODES * H_DIM * 2);
    u16*     aggbf  = (u16*)p;     p += align256((size_t)N_NODES * H_DIM * 2);
    float*   snode  = (float*)p;   p += align256((size_t)N_NODES * 4);
    u16*     W0p    = (u16*)p;     p += align256((size_t)(2 * F_IN) * H_DIM * 2);
    u16*     W1p    = (u16*)p;     p += align256((size_t)(2 * H_DIM) * H_DIM * 2);
    float*   bcc    = (float*)p;   p += align256(256 * 4);

    // fused prep (cvt + bias/binCnt + packw0 + packw1 + bounds)
    prep_kernel<<<CVT_BLOCKS + 1 + PW0_BLOCKS + PW1_BLOCKS + BND_BLOCKS, 256, 0, stream>>>(
        x, xbf, lin_l0_b, res0_b, lin_l1_b, res1_b, bcc, binCnt,
        lin_l0_w, lin_r0_w, res0_w, W0p, lin_l1_w, lin_r1_w, res1_w, W1p,
        batch, gstart);

    // two-phase edge bucketing
    partition_kernel<<<(N_EDGES + CHUNK - 1) / CHUNK, 256, 0, stream>>>(src, dst, binCnt, binned);
    fillbin_kernel<<<NBINS, 256, 0, stream>>>(binned, binCnt, bucket, degv);

    const int nTiles = (N_NODES + 63) / 64;

    // layer 0
    gather_kernel<F_IN><<<(N_NODES * 64 + 255) / 256, 256, 0, stream>>>(xbf, bucket, degv, aggbf);
    layer_mfma_kernel<F_IN, true, false><<<nTiles, 256, 0, stream>>>(
        aggbf, xbf, W0p, bcc, ln0_g, ln0_b, nullptr, h0bf, nullptr);

    // layer 1 (fused with out_w dot -> per-node scalar)
    gather_kernel<H_DIM><<<(N_NODES * 64 + 255) / 256, 256, 0, stream>>>(h0bf, bucket, degv, aggbf);
    layer_mfma_kernel<H_DIM, false, true><<<nTiles, 256, 0, stream>>>(
        aggbf, h0bf, W1p, bcc + 128, ln1_g, ln1_b, out_w, nullptr, snode);

    // per-graph mean + bias
    graph_mean_kernel<<<N_GRAPHS, 64, 0, stream>>>(snode, gstart, out_b, out);
}